// Round 13
// baseline (1285.143 us; speedup 1.0000x reference)
//
#include <hip/hip_runtime.h>

#define N_NODES 51200
#define N_EDGES 614400
#define ORIG 92
#define AFL 64
#define NFL 64
#define BINS 100
#define NCONV 3
#define BN_EPS 1e-5f
#define NTILES (N_EDGES / 16)     // 38400 tiles of 16 edges
#define NGROUPS (NTILES / 2)      // 19200 groups of 2 tiles (32 edges)
#define EK_BLOCK 768
#define EK_WAVES 12
#define EK_GRID 256
#define EK_STRIDE (EK_GRID * EK_WAVES)   // 3072 waves

typedef __attribute__((ext_vector_type(8))) short bf8;   // 8 bf16 (4 VGPRs)
typedef __attribute__((ext_vector_type(4))) float f32x4;

// ---------- bf16 helpers (bf16 = top 16 bits of fp32, RNE) ----------
__device__ __forceinline__ float bflo(unsigned int u) { return __uint_as_float(u << 16); }
__device__ __forceinline__ float bfhi(unsigned int u) { return __uint_as_float(u & 0xffff0000u); }
__device__ __forceinline__ unsigned int f2bf(float f) {
    unsigned int u = __float_as_uint(f);
    return (u + 0x7fffu + ((u >> 16) & 1u)) >> 16;
}
__device__ __forceinline__ short bfs(float f) { return (short)f2bf(f); }

// ---------------------------- CSR build (once per launch) ----------------------------
__global__ __launch_bounds__(256) void hist_kernel(const int* __restrict__ ei,
                                                   int* __restrict__ cnt)
{
    int e = blockIdx.x * 256 + threadIdx.x;
    atomicAdd(&cnt[ei[N_EDGES + e]], 1);
}

__global__ __launch_bounds__(1024) void scan_kernel(int* __restrict__ cnt_cursor,
                                                    int* __restrict__ rowptr)
{
    __shared__ int part[1024];
    const int t = threadIdx.x;
    const int base = t * 50;
    int s = 0;
#pragma unroll 10
    for (int i = 0; i < 50; ++i) s += cnt_cursor[base + i];
    part[t] = s;
    __syncthreads();
    for (int off = 1; off < 1024; off <<= 1) {
        int v = (t >= off) ? part[t - off] : 0;
        __syncthreads();
        part[t] += v;
        __syncthreads();
    }
    int run = (t == 0) ? 0 : part[t - 1];
    for (int i = 0; i < 50; ++i) {
        int c = cnt_cursor[base + i];
        rowptr[base + i] = run;
        cnt_cursor[base + i] = run;   // cursor init
        run += c;
    }
    if (t == 1023) rowptr[N_NODES] = run;
}

__global__ __launch_bounds__(256) void permbuild_kernel(const int* __restrict__ ei,
                                                        int* __restrict__ cursor,
                                                        int* __restrict__ perm)
{
    int e = blockIdx.x * 256 + threadIdx.x;
    int d = ei[N_EDGES + e];
    int pos = atomicAdd(&cursor[d], 1);
    perm[pos] = e;
}

__global__ __launch_bounds__(256) void gather_sorted_kernel(
    const int* __restrict__ perm, const float* __restrict__ ea,
    const int* __restrict__ ei,
    float* __restrict__ ea_s, int* __restrict__ src_s, int* __restrict__ dst_s)
{
    int i = blockIdx.x * 256 + threadIdx.x;
    int e = perm[i];
    ea_s[i] = ea[e];
    src_s[i] = ei[e];
    dst_s[i] = ei[N_EDGES + e];
}

// ---------------------------- embedding (fp32 + bf16 copies) ----------------------------
__global__ __launch_bounds__(256) void embed_kernel(
    const float* __restrict__ x, const float* __restrict__ att,
    const float* __restrict__ W, const float* __restrict__ b,
    float* __restrict__ h0, unsigned short* __restrict__ hbf)
{
    const int wave = threadIdx.x >> 6, lane = threadIdx.x & 63;
    const int gw = blockIdx.x * 4 + wave;
    const float bv = b[lane];
    for (int n = gw; n < N_NODES; n += gridDim.x * 4) {
        const float* xr = x + (size_t)n * ORIG;
        float acc = bv;
        for (int k = 0; k < ORIG; ++k)
            acc = fmaf(xr[k] * att[k], W[k * AFL + lane], acc);
        h0[(size_t)n * AFL + lane] = acc;
        hbf[(size_t)n * AFL + lane] = (unsigned short)f2bf(acc);
    }
}

// ---------------------------- MFMA edge kernel ----------------------------
// R13: 768-thread blocks (12 waves share one 95 KB weight copy -> 3 waves/SIMD)
// with the two R12 regressions fixed: launch_bounds(768,4) pins VGPR cap at 128
// (R11's measured natural pressure -> no scratch spills; R12's (768,3) hint
// drove the allocator to 84 VGPRs and +270 MB spill traffic), and SBS=138
// shorts = 69 dwords (odd -> conflict-free; R12's 136 = 68 dwords aliased
// 8 rows/bank-group, tripling SQ_LDS_BANK_CONFLICT). LDS total 148.2 KB.
#define SBS 138

__global__ __launch_bounds__(EK_BLOCK, 4) void edge_kernel(
    const float* __restrict__ ea_s, const int* __restrict__ src_s,
    const int* __restrict__ dst_s,
    const unsigned short* __restrict__ hbf,
    const float* __restrict__ w1, const float* __restrict__ b1,
    const float* __restrict__ w2, const float* __restrict__ b2,
    const float* __restrict__ alpha_p, const float* __restrict__ lut,
    const float* __restrict__ fcW, const float* __restrict__ fcb,
    short* __restrict__ zo, float* __restrict__ stats)
{
    __shared__ short sW2f[7 * 4 * 64 * 8];      // 28672 B
    __shared__ short sLutf[4 * 4 * 64 * 8];     // 16384 B
    __shared__ short sFcf[6 * 8 * 64 * 8];      // 49152 B
    __shared__ float sW1[128], sB1v[128];       // 1024 B (fp32, zero-padded)
    __shared__ short sBuf[EK_WAVES][16 * SBS];  // 52992 B  total 148224 B

    const int tid = threadIdx.x;
    for (int i = tid; i < 1792; i += EK_BLOCK) {     // W2^T fragments
        int t = i >> 8, rem = i & 255, s = rem >> 6, le = rem & 63;
        int n = 16 * t + (le & 15);
        int kb = 32 * s + ((le >> 4) << 3);
        short* d = &sW2f[i * 8];
#pragma unroll
        for (int j = 0; j < 8; ++j) {
            int k = kb + j;
            d[j] = bfs((n < BINS && k < BINS) ? w2[k * BINS + n] : 0.f);
        }
    }
    for (int i = tid; i < 1024; i += EK_BLOCK) {     // lut^T fragments
        int t = i >> 8, rem = i & 255, s = rem >> 6, le = rem & 63;
        int n = 16 * t + (le & 15);
        int kb = 32 * s + ((le >> 4) << 3);
        short* d = &sLutf[i * 8];
#pragma unroll
        for (int j = 0; j < 8; ++j) {
            int k = kb + j;
            d[j] = bfs(k < BINS ? lut[k * NFL + n] : 0.f);
        }
    }
    for (int i = tid; i < 3072; i += EK_BLOCK) {     // fcW^T fragments
        int s = i >> 9, rem = i & 511, t = rem >> 6, le = rem & 63;
        int n = 16 * t + (le & 15);
        int kb = 32 * s + ((le >> 4) << 3);
        short* d = &sFcf[i * 8];
#pragma unroll
        for (int j = 0; j < 8; ++j)
            d[j] = bfs(fcW[(kb + j) * 128 + n]);
    }
    if (tid < 128) {                                  // w1/b1 fp32, zero-pad k>=100
        sW1[tid]  = (tid < BINS) ? w1[tid] : 0.f;
        sB1v[tid] = (tid < BINS) ? b1[tid] : 0.f;
    }
    __syncthreads();

    const int wave = tid >> 6, lane = tid & 63;
    const int ln = lane & 15, q = lane >> 4;
    short* sB = &sBuf[wave][0];
    const float alpha = alpha_p[0];

    float w1c[7], b1c[7], b2c[7];           // C-layout col = ln + 16t
#pragma unroll
    for (int t = 0; t < 7; ++t) {
        int c = ln + 16 * t;
        bool v = c < BINS;
        w1c[t] = v ? w1[c] : 0.f;
        b1c[t] = v ? b1[c] : 0.f;
        b2c[t] = v ? b2[c] : 0.f;
    }
    float fbias[8];
#pragma unroll
    for (int t = 0; t < 8; ++t) fbias[t] = fcb[ln + 16 * t];

    float ss[8], sq[8];
#pragma unroll
    for (int t = 0; t < 8; ++t) { ss[t] = 0.f; sq[t] = 0.f; }

    int g = blockIdx.x * EK_WAVES + wave;
    // ---- prologue: group indices (per-lane: edge ln of each tile) ----
    float avA = 0.f, avB = 0.f;
    int snA = 0, dnA = 0, snB = 0, dnB = 0;
    if (g < NGROUPS) {
        int b0 = g * 32 + ln;
        avA = ea_s[b0];      snA = src_s[b0];      dnA = dst_s[b0];
        avB = ea_s[b0 + 16]; snB = src_s[b0 + 16]; dnB = dst_s[b0 + 16];
    }

    for (; g < NGROUPS; g += EK_STRIDE) {
        const int ebase = g * 32;
        // ---- PHASE 0: direct per-lane h loads for cat (A-frag layout:
        //      cat[m=ln][k=32s+8q+j], s=0,1 -> h[dst], s=2,3 -> h[src]) ----
        bf8 acA[6], acB[6];
        acA[0] = *(const bf8*)&hbf[(size_t)dnA * 64 + 8 * q];
        acA[1] = *(const bf8*)&hbf[(size_t)dnA * 64 + 32 + 8 * q];
        acA[2] = *(const bf8*)&hbf[(size_t)snA * 64 + 8 * q];
        acA[3] = *(const bf8*)&hbf[(size_t)snA * 64 + 32 + 8 * q];
        acB[0] = *(const bf8*)&hbf[(size_t)dnB * 64 + 8 * q];
        acB[1] = *(const bf8*)&hbf[(size_t)dnB * 64 + 32 + 8 * q];
        acB[2] = *(const bf8*)&hbf[(size_t)snB * 64 + 8 * q];
        acB[3] = *(const bf8*)&hbf[(size_t)snB * 64 + 32 + 8 * q];
        // next-group index prefetch
        const int gn = g + EK_STRIDE;
        const int gs = (gn < NGROUPS) ? gn : g;
        const int bN = gs * 32 + ln;
        float avAN = ea_s[bN];      int snAN = src_s[bN];      int dnAN = dst_s[bN];
        float avBN = ea_s[bN + 16]; int snBN = src_s[bN + 16]; int dnBN = dst_s[bN + 16];

        // ---- PHASE 1: v2 A-frags DIRECT (av per-lane; w1/b1 broadcast LDS) ----
        bf8 aA[4], aB[4];
#pragma unroll
        for (int s = 0; s < 4; ++s) {
            const int kb = 32 * s + 8 * q;
            float4 w0 = *(const float4*)&sW1[kb];
            float4 w4 = *(const float4*)&sW1[kb + 4];
            float4 c0 = *(const float4*)&sB1v[kb];
            float4 c4 = *(const float4*)&sB1v[kb + 4];
            float wk[8] = {w0.x, w0.y, w0.z, w0.w, w4.x, w4.y, w4.z, w4.w};
            float ck[8] = {c0.x, c0.y, c0.z, c0.w, c4.x, c4.y, c4.z, c4.w};
#pragma unroll
            for (int j = 0; j < 8; ++j) {
                float vA = fmaf(avA, wk[j], ck[j]);
                vA = vA > 0.f ? vA : 0.01f * vA;
                aA[s][j] = bfs(vA);
                float vB = fmaf(avB, wk[j], ck[j]);
                vB = vB > 0.f ? vB : 0.01f * vB;
                aB[s][j] = bfs(vB);
            }
        }
        // C-layout acc init: alpha*v2 + b2 (rows = edges q*4+r)
        f32x4 accA[7], accB[7];
#pragma unroll
        for (int r = 0; r < 4; ++r) {
            float arA = __shfl(avA, q * 4 + r, 64);
            float arB = __shfl(avB, q * 4 + r, 64);
#pragma unroll
            for (int t = 0; t < 7; ++t) {
                float vA = fmaf(arA, w1c[t], b1c[t]);
                vA = vA > 0.f ? vA : 0.01f * vA;
                accA[t][r] = fmaf(alpha, vA, b2c[t]);
                float vB = fmaf(arB, w1c[t], b1c[t]);
                vB = vB > 0.f ? vB : 0.01f * vB;
                accB[t][r] = fmaf(alpha, vB, b2c[t]);
            }
        }
        // ---- PHASE 2: v3 MFMAs (shared B reads) ----
#pragma unroll
        for (int s = 0; s < 4; ++s)
#pragma unroll
            for (int t = 0; t < 7; ++t) {
                bf8 bw = *(const bf8*)&sW2f[((t * 4 + s) * 64 + lane) * 8];
                accA[t] = __builtin_amdgcn_mfma_f32_16x16x32_bf16(aA[s], bw, accA[t], 0, 0, 0);
                accB[t] = __builtin_amdgcn_mfma_f32_16x16x32_bf16(aB[s], bw, accB[t], 0, 0, 0);
            }
        // ---- PHASE 3: softmax (no max-reduce; shift-invariant, |v3| small) ----
#pragma unroll
        for (int r = 0; r < 4; ++r) {
            float evA[7], evB[7], sumA = 0.f, sumB = 0.f;
#pragma unroll
            for (int t = 0; t < 7; ++t) {
                bool on = (t < 6) || (ln < 4);
                evA[t] = on ? __expf(accA[t][r]) : 0.f; sumA += evA[t];
                evB[t] = on ? __expf(accB[t][r]) : 0.f; sumB += evB[t];
            }
#pragma unroll
            for (int o = 8; o >= 1; o >>= 1) {
                sumA += __shfl_xor(sumA, o, 16);
                sumB += __shfl_xor(sumB, o, 16);
            }
            float iA = 1.0f / sumA, iB = 1.0f / sumB;
#pragma unroll
            for (int t = 0; t < 7; ++t) { accA[t][r] = evA[t] * iA; accB[t][r] = evB[t] * iB; }
        }
        // ---- PHASE 4: p transposes (zero pad cols 100..127 first; z-stage
        //      clobbered it last iteration) ----
#pragma unroll
        for (int i = 0; i < 7; ++i) {
            int idx = i * 64 + lane;
            int row = idx / 28, c = 100 + (idx - row * 28);
            sB[row * SBS + c] = 0;
        }
#pragma unroll
        for (int r = 0; r < 4; ++r)
#pragma unroll
            for (int t = 0; t < 7; ++t)
                if (t < 6 || ln < 4) sB[(q * 4 + r) * SBS + ln + 16 * t] = bfs(accA[t][r]);
        bf8 apA[4];
#pragma unroll
        for (int s = 0; s < 4; ++s) apA[s] = *(const bf8*)&sB[ln * SBS + 32 * s + 8 * q];
#pragma unroll
        for (int r = 0; r < 4; ++r)
#pragma unroll
            for (int t = 0; t < 7; ++t)
                if (t < 6 || ln < 4) sB[(q * 4 + r) * SBS + ln + 16 * t] = bfs(accB[t][r]);
        bf8 apB[4];
#pragma unroll
        for (int s = 0; s < 4; ++s) apB[s] = *(const bf8*)&sB[ln * SBS + 32 * s + 8 * q];
        // ---- PHASE 5: e = p @ lut (shared B reads) ----
        f32x4 eaccA[4], eaccB[4];
#pragma unroll
        for (int t = 0; t < 4; ++t) {
            eaccA[t] = (f32x4){0.f, 0.f, 0.f, 0.f};
            eaccB[t] = (f32x4){0.f, 0.f, 0.f, 0.f};
        }
#pragma unroll
        for (int s = 0; s < 4; ++s)
#pragma unroll
            for (int t = 0; t < 4; ++t) {
                bf8 bl = *(const bf8*)&sLutf[((t * 4 + s) * 64 + lane) * 8];
                eaccA[t] = __builtin_amdgcn_mfma_f32_16x16x32_bf16(apA[s], bl, eaccA[t], 0, 0, 0);
                eaccB[t] = __builtin_amdgcn_mfma_f32_16x16x32_bf16(apB[s], bl, eaccB[t], 0, 0, 0);
            }
        // ---- PHASE 6: e transposes reuse p's region (cols 0..63; p consumed;
        //      in-order DS makes read-then-overwrite safe) ----
#pragma unroll
        for (int t = 0; t < 4; ++t)
#pragma unroll
            for (int r = 0; r < 4; ++r)
                sB[(q * 4 + r) * SBS + ln + 16 * t] = bfs(eaccA[t][r]);
        acA[4] = *(const bf8*)&sB[ln * SBS + 8 * q];
        acA[5] = *(const bf8*)&sB[ln * SBS + 32 + 8 * q];
#pragma unroll
        for (int t = 0; t < 4; ++t)
#pragma unroll
            for (int r = 0; r < 4; ++r)
                sB[(q * 4 + r) * SBS + ln + 16 * t] = bfs(eaccB[t][r]);
        acB[4] = *(const bf8*)&sB[ln * SBS + 8 * q];
        acB[5] = *(const bf8*)&sB[ln * SBS + 32 + 8 * q];
        // ---- PHASE 7: z = cat @ fcW + fcb (shared B reads) ----
        f32x4 zaccA[8], zaccB[8];
#pragma unroll
        for (int t = 0; t < 8; ++t) {
            zaccA[t] = (f32x4){fbias[t], fbias[t], fbias[t], fbias[t]};
            zaccB[t] = (f32x4){fbias[t], fbias[t], fbias[t], fbias[t]};
        }
#pragma unroll
        for (int s = 0; s < 6; ++s)
#pragma unroll
            for (int t = 0; t < 8; ++t) {
                bf8 bw = *(const bf8*)&sFcf[((s * 8 + t) * 64 + lane) * 8];
                zaccA[t] = __builtin_amdgcn_mfma_f32_16x16x32_bf16(acA[s], bw, zaccA[t], 0, 0, 0);
                zaccB[t] = __builtin_amdgcn_mfma_f32_16x16x32_bf16(acB[s], bw, zaccB[t], 0, 0, 0);
            }
        // ---- PHASE 8: stats + stage + writeout zA ----
#pragma unroll
        for (int t = 0; t < 8; ++t)
#pragma unroll
            for (int r = 0; r < 4; ++r) {
                float zv = zaccA[t][r];
                ss[t] += zv; sq[t] = fmaf(zv, zv, sq[t]);
                sB[(q * 4 + r) * SBS + ln + 16 * t] = bfs(zv);
            }
#pragma unroll
        for (int i = 0; i < 4; ++i) {
            int idx = i * 64 + lane;
            int row = idx >> 4, seg = idx & 15;
            bf8 v = *(const bf8*)&sB[row * SBS + seg * 8];
            *(bf8*)&zo[(size_t)(ebase + row) * 128 + seg * 8] = v;
        }
        // ---- PHASE 9: stats + stage + writeout zB ----
#pragma unroll
        for (int t = 0; t < 8; ++t)
#pragma unroll
            for (int r = 0; r < 4; ++r) {
                float zv = zaccB[t][r];
                ss[t] += zv; sq[t] = fmaf(zv, zv, sq[t]);
                sB[(q * 4 + r) * SBS + ln + 16 * t] = bfs(zv);
            }
#pragma unroll
        for (int i = 0; i < 4; ++i) {
            int idx = i * 64 + lane;
            int row = idx >> 4, seg = idx & 15;
            bf8 v = *(const bf8*)&sB[row * SBS + seg * 8];
            *(bf8*)&zo[(size_t)(ebase + 16 + row) * 128 + seg * 8] = v;
        }
        // ---- rotate prefetched indices ----
        avA = avAN; snA = snAN; dnA = dnAN;
        avB = avBN; snB = snBN; dnB = dnBN;
    }

    // ---- bn1 stats reduction (12 waves) ----
#pragma unroll
    for (int t = 0; t < 8; ++t) {
        ss[t] += __shfl_xor(ss[t], 16, 64); ss[t] += __shfl_xor(ss[t], 32, 64);
        sq[t] += __shfl_xor(sq[t], 16, 64); sq[t] += __shfl_xor(sq[t], 32, 64);
    }
    __syncthreads();
    float* sred = (float*)&sBuf[0][0];    // 3072 floats = 12288 B (fits in sBuf)
    if (q == 0) {
#pragma unroll
        for (int t = 0; t < 8; ++t) {
            sred[wave * 128 + ln + 16 * t] = ss[t];
            sred[1536 + wave * 128 + ln + 16 * t] = sq[t];
        }
    }
    __syncthreads();
    if (tid < 256) {
        int base = (tid < 128) ? 0 : 1536;
        int col = tid & 127;
        float s = 0.f;
#pragma unroll
        for (int w = 0; w < EK_WAVES; ++w) s += sred[base + w * 128 + col];
        atomicAdd(&stats[tid], s);
    }
}

// ------------- bn finalize -------------
__global__ void bn_fin_kernel(const float* __restrict__ stats,
                              const float* __restrict__ g, const float* __restrict__ b,
                              float* __restrict__ bnp, int C, float invN)
{
    int c = threadIdx.x;
    if (c >= C) return;
    float mu = stats[c] * invN;
    float var = stats[C + c] * invN - mu * mu;
    float sc = g[c] * rsqrtf(var + BN_EPS);
    bnp[c] = sc;
    bnp[C + c] = b[c] - mu * sc;
}

// ------------- CSR aggregate: wave per node, zero atomics (R6 proven form) -------------
__global__ __launch_bounds__(256) void aggregate_kernel(
    const unsigned int* __restrict__ z32, const int* __restrict__ rowptr,
    const float* __restrict__ bnp, float* __restrict__ aggr)
{
    const int n = blockIdx.x * 4 + (threadIdx.x >> 6);
    const int lane = threadIdx.x & 63;
    const int f2 = lane & 31, slot = lane >> 5, f = 2 * f2;
    const float sc0 = bnp[f], sc1 = bnp[f + 1];
    const float sh0 = bnp[128 + f], sh1 = bnp[128 + f + 1];
    const float tc0 = bnp[64 + f], tc1 = bnp[64 + f + 1];
    const float th0 = bnp[192 + f], th1 = bnp[192 + f + 1];
    const int s = rowptr[n], e_end = rowptr[n + 1];
    float a0 = 0.f, a1 = 0.f;
    for (int e = s + slot; e < e_end; e += 2) {
        unsigned int ua = z32[(size_t)e * 64 + f2];
        unsigned int ub = z32[(size_t)e * 64 + 32 + f2];
        float zf0 = fmaf(bflo(ua), sc0, sh0);
        float zf1 = fmaf(bfhi(ua), sc1, sh1);
        float zc0 = fmaf(bflo(ub), tc0, th0);
        float zc1 = fmaf(bfhi(ub), tc1, th1);
        a0 += fmaxf(zf0, 0.f) * fmaxf(zc0, 0.f);
        a1 += fmaxf(zf1, 0.f) * fmaxf(zc1, 0.f);
    }
    a0 += __shfl_xor(a0, 32, 64);
    a1 += __shfl_xor(a1, 32, 64);
    if (slot == 0) {
        float2 w; w.x = a0; w.y = a1;
        *(float2*)&aggr[(size_t)n * 64 + f] = w;
    }
}

// ------------- column stats over [rows,64] -------------
__global__ __launch_bounds__(256) void colstats64_kernel(
    const float* __restrict__ x, int rows, float* __restrict__ stats)
{
    int f = threadIdx.x & 63, sub = threadIdx.x >> 6;
    float s = 0.f, q = 0.f;
    for (int r = blockIdx.x * 4 + sub; r < rows; r += gridDim.x * 4) {
        float v = x[(size_t)r * 64 + f];
        s += v; q = fmaf(v, v, q);
    }
    __shared__ float ls[4][64], lq[4][64];
    ls[sub][f] = s; lq[sub][f] = q;
    __syncthreads();
    if (sub == 0) {
        s = ls[0][f] + ls[1][f] + ls[2][f] + ls[3][f];
        q = lq[0][f] + lq[1][f] + lq[2][f] + lq[3][f];
        atomicAdd(&stats[f], s);
        atomicAdd(&stats[64 + f], q);
    }
}

// ------------- h_next = relu(h + bn2(aggr))  (fp32 + bf16 copies) -------------
__global__ __launch_bounds__(256) void update_kernel(
    const float* __restrict__ h, const float* __restrict__ aggr,
    const float* __restrict__ bnp, float* __restrict__ hout,
    unsigned short* __restrict__ hbf)
{
    int t = blockIdx.x * 256 + threadIdx.x;
    int f = t & 63;
    float v = fmaf(aggr[t], bnp[f], bnp[64 + f]);
    float r = fmaxf(h[t] + v, 0.f);
    hout[t] = r;
    hbf[t] = (unsigned short)f2bf(r);
}

// ------------- pooling -------------
__global__ __launch_bounds__(256) void pool_kernel(
    const float* __restrict__ hbuf, const float* __restrict__ ppW,
    const float* __restrict__ ppb, float* __restrict__ out)
{
    const int l = blockIdx.x >> 7, b = blockIdx.x & 127;
    const int wave = threadIdx.x >> 6, lane = threadIdx.x & 63;
    float wcol[64];
#pragma unroll
    for (int k = 0; k < 64; ++k) wcol[k] = ppW[k * 64 + lane];
    const float bias = ppb[lane];
    const float* base = hbuf + ((size_t)l * N_NODES + (size_t)b * 400) * 64;
    __shared__ float srow[4][2][64];
    __shared__ float sacc[4][64];
    float acc = 0.f;
    for (int r = wave * 2; r < 400; r += 8) {
        srow[wave][0][lane] = base[(size_t)r * 64 + lane];
        srow[wave][1][lane] = base[(size_t)r * 64 + 64 + lane];
        float lg0 = bias, lg1 = bias;
#pragma unroll
        for (int k4 = 0; k4 < 64; k4 += 4) {
            float4 a = *(const float4*)&srow[wave][0][k4];
            float4 c = *(const float4*)&srow[wave][1][k4];
            lg0 = fmaf(a.x, wcol[k4 + 0], lg0); lg1 = fmaf(c.x, wcol[k4 + 0], lg1);
            lg0 = fmaf(a.y, wcol[k4 + 1], lg0); lg1 = fmaf(c.y, wcol[k4 + 1], lg1);
            lg0 = fmaf(a.z, wcol[k4 + 2], lg0); lg1 = fmaf(c.z, wcol[k4 + 2], lg1);
            lg0 = fmaf(a.w, wcol[k4 + 3], lg0); lg1 = fmaf(c.w, wcol[k4 + 3], lg1);
        }
        float m0 = lg0, m1 = lg1;
#pragma unroll
        for (int o = 32; o >= 1; o >>= 1) {
            m0 = fmaxf(m0, __shfl_xor(m0, o, 64));
            m1 = fmaxf(m1, __shfl_xor(m1, o, 64));
        }
        float e0 = __expf(lg0 - m0), e1 = __expf(lg1 - m1);
        float s0 = e0, s1 = e1;
#pragma unroll
        for (int o = 32; o >= 1; o >>= 1) {
            s0 += __shfl_xor(s0, o, 64);
            s1 += __shfl_xor(s1, o, 64);
        }
        acc += e0 * (1.0f / s0) + e1 * (1.0f / s1);
    }
    sacc[wave][lane] = acc;
    __syncthreads();
    if (wave == 0) {
        float t = sacc[0][lane] + sacc[1][lane] + sacc[2][lane] + sacc[3][lane];
        atomicAdd(&out[(size_t)b * 64 + lane], t);
    }
}

// ---------------------------------------------------------------------------
extern "C" void kernel_launch(void* const* d_in, const int* in_sizes, int n_in,
                              void* d_out, int out_size, void* d_ws, size_t ws_size,
                              hipStream_t stream)
{
    const float* x        = (const float*)d_in[0];
    const int*   ei       = (const int*)d_in[1];
    const float* ea       = (const float*)d_in[2];
    const float* att      = (const float*)d_in[4];
    const float* embW     = (const float*)d_in[5];
    const float* embB     = (const float*)d_in[6];
    const float* ad_w1    = (const float*)d_in[7];
    const float* ad_b1    = (const float*)d_in[8];
    const float* ad_w2    = (const float*)d_in[9];
    const float* ad_b2    = (const float*)d_in[10];
    const float* ad_alpha = (const float*)d_in[11];
    const float* ad_lut   = (const float*)d_in[12];
    const float* fc_W     = (const float*)d_in[13];
    const float* fc_b     = (const float*)d_in[14];
    const float* bn1_g    = (const float*)d_in[15];
    const float* bn1_b    = (const float*)d_in[16];
    const float* bn2_g    = (const float*)d_in[17];
    const float* bn2_b    = (const float*)d_in[18];
    const float* ppW      = (const float*)d_in[19];
    const float* ppb      = (const float*)d_in[20];
    float* out = (float*)d_out;

    char* ws = (char*)d_ws;
    float* hbuf   = (float*)ws;                          // 52,428,800 B
    short* zU     = (short*)(ws + 52428800);             // 157,286,400 B
    float* aggr   = (float*)(ws + 209715200);            // 13,107,200 B
    float* stats1 = (float*)(ws + 222822400);            // 256 f
    float* bnp1   = stats1 + 256;                        // 256 f
    float* stats2 = bnp1 + 256;                          // 128 f
    float* bnp2   = stats2 + 128;                        // 128 f (pad to 222826496)
    int*   rowptr = (int*)(ws + 222826496);              // 51201 ints
    int*   cursor = (int*)(ws + 223031360);              // 51200 ints
    float* ea_s   = (float*)(ws + 223236160);            // 614400 f
    int*   src_s  = (int*)(ws + 225693760);              // 614400 ints
    int*   dst_s  = (int*)(ws + 228151360);              // 614400 ints
    // perm only used during CSR build (before embed); hbf written after -> union
    int*   perm   = (int*)(ws + 230608960);              // 614400 ints
    unsigned short* hbf = (unsigned short*)(ws + 230608960);   // 6,553,600 B

    // ---- CSR build + sorted edge arrays (dst is launch-constant) ----
    hipMemsetAsync(cursor, 0, N_NODES * sizeof(int), stream);
    hist_kernel<<<N_EDGES / 256, 256, 0, stream>>>(ei, cursor);
    scan_kernel<<<1, 1024, 0, stream>>>(cursor, rowptr);
    permbuild_kernel<<<N_EDGES / 256, 256, 0, stream>>>(ei, cursor, perm);
    gather_sorted_kernel<<<N_EDGES / 256, 256, 0, stream>>>(perm, ea, ei, ea_s, src_s, dst_s);

    hipMemsetAsync(out, 0, 128 * 64 * sizeof(float), stream);
    embed_kernel<<<512, 256, 0, stream>>>(x, att, embW, embB, hbuf, hbf);

    for (int l = 0; l < NCONV; ++l) {
        float* h  = hbuf + (size_t)l * N_NODES * AFL;
        float* hn = h + (size_t)N_NODES * AFL;
        hipMemsetAsync(stats1, 0, 768 * 4, stream);      // zeroes stats1 + bnp1 + stats2
        edge_kernel<<<EK_GRID, EK_BLOCK, 0, stream>>>(
            ea_s, src_s, dst_s, hbf,
            ad_w1 + l * BINS, ad_b1 + l * BINS,
            ad_w2 + l * BINS * BINS, ad_b2 + l * BINS,
            ad_alpha + l, ad_lut + l * BINS * NFL,
            fc_W + l * 192 * 128, fc_b + l * 128,
            zU, stats1);
        bn_fin_kernel<<<1, 128, 0, stream>>>(stats1, bn1_g + l * 128, bn1_b + l * 128,
                                             bnp1, 128, 1.0f / N_EDGES);
        aggregate_kernel<<<N_NODES / 4, 256, 0, stream>>>((const unsigned int*)zU, rowptr,
                                                          bnp1, aggr);
        colstats64_kernel<<<256, 256, 0, stream>>>(aggr, N_NODES, stats2);
        bn_fin_kernel<<<1, 128, 0, stream>>>(stats2, bn2_g + l * 64, bn2_b + l * 64,
                                             bnp2, 64, 1.0f / N_NODES);
        update_kernel<<<N_NODES * 64 / 256, 256, 0, stream>>>(h, aggr, bnp2, hn, hbf);
    }

    pool_kernel<<<512, 256, 0, stream>>>(hbuf, ppW, ppb, out);
}

// Round 14
// 1277.209 us; speedup vs baseline: 1.0062x; 1.0062x over previous
//
#include <hip/hip_runtime.h>

#define N_NODES 51200
#define N_EDGES 614400
#define ORIG 92
#define AFL 64
#define NFL 64
#define BINS 100
#define NCONV 3
#define BN_EPS 1e-5f
#define NTILES (N_EDGES / 16)     // 38400 tiles of 16 edges
#define NGROUPS (NTILES / 2)      // 19200 groups of 2 tiles (32 edges)
#define EK_BLOCK 768
#define EK_WAVES 12
#define EK_GRID 256
#define EK_STRIDE (EK_GRID * EK_WAVES)   // 3072 waves

typedef __attribute__((ext_vector_type(8))) short bf8;   // 8 bf16 (4 VGPRs)
typedef __attribute__((ext_vector_type(4))) float f32x4;

// ---------- bf16 helpers (bf16 = top 16 bits of fp32, RNE) ----------
__device__ __forceinline__ float bflo(unsigned int u) { return __uint_as_float(u << 16); }
__device__ __forceinline__ float bfhi(unsigned int u) { return __uint_as_float(u & 0xffff0000u); }
__device__ __forceinline__ unsigned int f2bf(float f) {
    unsigned int u = __float_as_uint(f);
    return (u + 0x7fffu + ((u >> 16) & 1u)) >> 16;
}
__device__ __forceinline__ short bfs(float f) { return (short)f2bf(f); }

// ---------------------------- CSR build (once per launch) ----------------------------
__global__ __launch_bounds__(256) void hist_kernel(const int* __restrict__ ei,
                                                   int* __restrict__ cnt)
{
    int e = blockIdx.x * 256 + threadIdx.x;
    atomicAdd(&cnt[ei[N_EDGES + e]], 1);
}

__global__ __launch_bounds__(1024) void scan_kernel(int* __restrict__ cnt_cursor,
                                                    int* __restrict__ rowptr)
{
    __shared__ int part[1024];
    const int t = threadIdx.x;
    const int base = t * 50;
    int s = 0;
#pragma unroll 10
    for (int i = 0; i < 50; ++i) s += cnt_cursor[base + i];
    part[t] = s;
    __syncthreads();
    for (int off = 1; off < 1024; off <<= 1) {
        int v = (t >= off) ? part[t - off] : 0;
        __syncthreads();
        part[t] += v;
        __syncthreads();
    }
    int run = (t == 0) ? 0 : part[t - 1];
    for (int i = 0; i < 50; ++i) {
        int c = cnt_cursor[base + i];
        rowptr[base + i] = run;
        cnt_cursor[base + i] = run;   // cursor init
        run += c;
    }
    if (t == 1023) rowptr[N_NODES] = run;
}

__global__ __launch_bounds__(256) void permbuild_kernel(const int* __restrict__ ei,
                                                        int* __restrict__ cursor,
                                                        int* __restrict__ perm)
{
    int e = blockIdx.x * 256 + threadIdx.x;
    int d = ei[N_EDGES + e];
    int pos = atomicAdd(&cursor[d], 1);
    perm[pos] = e;
}

__global__ __launch_bounds__(256) void gather_sorted_kernel(
    const int* __restrict__ perm, const float* __restrict__ ea,
    const int* __restrict__ ei,
    float* __restrict__ ea_s, int* __restrict__ src_s, int* __restrict__ dst_s)
{
    int i = blockIdx.x * 256 + threadIdx.x;
    int e = perm[i];
    ea_s[i] = ea[e];
    src_s[i] = ei[e];
    dst_s[i] = ei[N_EDGES + e];
}

// ---------------------------- embedding (fp32 + bf16 copies) ----------------------------
__global__ __launch_bounds__(256) void embed_kernel(
    const float* __restrict__ x, const float* __restrict__ att,
    const float* __restrict__ W, const float* __restrict__ b,
    float* __restrict__ h0, unsigned short* __restrict__ hbf)
{
    const int wave = threadIdx.x >> 6, lane = threadIdx.x & 63;
    const int gw = blockIdx.x * 4 + wave;
    const float bv = b[lane];
    for (int n = gw; n < N_NODES; n += gridDim.x * 4) {
        const float* xr = x + (size_t)n * ORIG;
        float acc = bv;
        for (int k = 0; k < ORIG; ++k)
            acc = fmaf(xr[k] * att[k], W[k * AFL + lane], acc);
        h0[(size_t)n * AFL + lane] = acc;
        hbf[(size_t)n * AFL + lane] = (unsigned short)f2bf(acc);
    }
}

// ---------------------------- MFMA edge kernel ----------------------------
// R14: same 12-wave structure as R13, but VGPR allocation pinned with
// amdgpu_waves_per_eu(3,3). R12/R13 showed __launch_bounds__' min-waves arg
// only sets a FLOOR: the allocator's occupancy heuristic squeezed to 84 VGPRs
// targeting 6 waves/EU (2 blocks/CU) that LDS (148 KB -> 1 block/CU) can never
// deliver -> ~300 MB/dispatch scratch spill traffic. min=max=3 gives a 170-VGPR
// budget and stops the squeeze (natural pressure ~128, measured R11).
// SBS=138 shorts = 69 dwords (odd -> conflict-free, verified R13: 2.35M->0.81M).
#define SBS 138

__global__ __launch_bounds__(EK_BLOCK)
__attribute__((amdgpu_waves_per_eu(3, 3)))
void edge_kernel(
    const float* __restrict__ ea_s, const int* __restrict__ src_s,
    const int* __restrict__ dst_s,
    const unsigned short* __restrict__ hbf,
    const float* __restrict__ w1, const float* __restrict__ b1,
    const float* __restrict__ w2, const float* __restrict__ b2,
    const float* __restrict__ alpha_p, const float* __restrict__ lut,
    const float* __restrict__ fcW, const float* __restrict__ fcb,
    short* __restrict__ zo, float* __restrict__ stats)
{
    __shared__ short sW2f[7 * 4 * 64 * 8];      // 28672 B
    __shared__ short sLutf[4 * 4 * 64 * 8];     // 16384 B
    __shared__ short sFcf[6 * 8 * 64 * 8];      // 49152 B
    __shared__ float sW1[128], sB1v[128];       // 1024 B (fp32, zero-padded)
    __shared__ short sBuf[EK_WAVES][16 * SBS];  // 52992 B  total 148224 B

    const int tid = threadIdx.x;
    for (int i = tid; i < 1792; i += EK_BLOCK) {     // W2^T fragments
        int t = i >> 8, rem = i & 255, s = rem >> 6, le = rem & 63;
        int n = 16 * t + (le & 15);
        int kb = 32 * s + ((le >> 4) << 3);
        short* d = &sW2f[i * 8];
#pragma unroll
        for (int j = 0; j < 8; ++j) {
            int k = kb + j;
            d[j] = bfs((n < BINS && k < BINS) ? w2[k * BINS + n] : 0.f);
        }
    }
    for (int i = tid; i < 1024; i += EK_BLOCK) {     // lut^T fragments
        int t = i >> 8, rem = i & 255, s = rem >> 6, le = rem & 63;
        int n = 16 * t + (le & 15);
        int kb = 32 * s + ((le >> 4) << 3);
        short* d = &sLutf[i * 8];
#pragma unroll
        for (int j = 0; j < 8; ++j) {
            int k = kb + j;
            d[j] = bfs(k < BINS ? lut[k * NFL + n] : 0.f);
        }
    }
    for (int i = tid; i < 3072; i += EK_BLOCK) {     // fcW^T fragments
        int s = i >> 9, rem = i & 511, t = rem >> 6, le = rem & 63;
        int n = 16 * t + (le & 15);
        int kb = 32 * s + ((le >> 4) << 3);
        short* d = &sFcf[i * 8];
#pragma unroll
        for (int j = 0; j < 8; ++j)
            d[j] = bfs(fcW[(kb + j) * 128 + n]);
    }
    if (tid < 128) {                                  // w1/b1 fp32, zero-pad k>=100
        sW1[tid]  = (tid < BINS) ? w1[tid] : 0.f;
        sB1v[tid] = (tid < BINS) ? b1[tid] : 0.f;
    }
    __syncthreads();

    const int wave = tid >> 6, lane = tid & 63;
    const int ln = lane & 15, q = lane >> 4;
    short* sB = &sBuf[wave][0];
    const float alpha = alpha_p[0];

    float w1c[7], b1c[7], b2c[7];           // C-layout col = ln + 16t
#pragma unroll
    for (int t = 0; t < 7; ++t) {
        int c = ln + 16 * t;
        bool v = c < BINS;
        w1c[t] = v ? w1[c] : 0.f;
        b1c[t] = v ? b1[c] : 0.f;
        b2c[t] = v ? b2[c] : 0.f;
    }
    float fbias[8];
#pragma unroll
    for (int t = 0; t < 8; ++t) fbias[t] = fcb[ln + 16 * t];

    float ss[8], sq[8];
#pragma unroll
    for (int t = 0; t < 8; ++t) { ss[t] = 0.f; sq[t] = 0.f; }

    int g = blockIdx.x * EK_WAVES + wave;
    // ---- prologue: group indices (per-lane: edge ln of each tile) ----
    float avA = 0.f, avB = 0.f;
    int snA = 0, dnA = 0, snB = 0, dnB = 0;
    if (g < NGROUPS) {
        int b0 = g * 32 + ln;
        avA = ea_s[b0];      snA = src_s[b0];      dnA = dst_s[b0];
        avB = ea_s[b0 + 16]; snB = src_s[b0 + 16]; dnB = dst_s[b0 + 16];
    }

    for (; g < NGROUPS; g += EK_STRIDE) {
        const int ebase = g * 32;
        // ---- PHASE 0: direct per-lane h loads for cat (A-frag layout:
        //      cat[m=ln][k=32s+8q+j], s=0,1 -> h[dst], s=2,3 -> h[src]) ----
        bf8 acA[6], acB[6];
        acA[0] = *(const bf8*)&hbf[(size_t)dnA * 64 + 8 * q];
        acA[1] = *(const bf8*)&hbf[(size_t)dnA * 64 + 32 + 8 * q];
        acA[2] = *(const bf8*)&hbf[(size_t)snA * 64 + 8 * q];
        acA[3] = *(const bf8*)&hbf[(size_t)snA * 64 + 32 + 8 * q];
        acB[0] = *(const bf8*)&hbf[(size_t)dnB * 64 + 8 * q];
        acB[1] = *(const bf8*)&hbf[(size_t)dnB * 64 + 32 + 8 * q];
        acB[2] = *(const bf8*)&hbf[(size_t)snB * 64 + 8 * q];
        acB[3] = *(const bf8*)&hbf[(size_t)snB * 64 + 32 + 8 * q];
        // next-group index prefetch
        const int gn = g + EK_STRIDE;
        const int gs = (gn < NGROUPS) ? gn : g;
        const int bN = gs * 32 + ln;
        float avAN = ea_s[bN];      int snAN = src_s[bN];      int dnAN = dst_s[bN];
        float avBN = ea_s[bN + 16]; int snBN = src_s[bN + 16]; int dnBN = dst_s[bN + 16];

        // ---- PHASE 1: v2 A-frags DIRECT (av per-lane; w1/b1 broadcast LDS) ----
        bf8 aA[4], aB[4];
#pragma unroll
        for (int s = 0; s < 4; ++s) {
            const int kb = 32 * s + 8 * q;
            float4 w0 = *(const float4*)&sW1[kb];
            float4 w4 = *(const float4*)&sW1[kb + 4];
            float4 c0 = *(const float4*)&sB1v[kb];
            float4 c4 = *(const float4*)&sB1v[kb + 4];
            float wk[8] = {w0.x, w0.y, w0.z, w0.w, w4.x, w4.y, w4.z, w4.w};
            float ck[8] = {c0.x, c0.y, c0.z, c0.w, c4.x, c4.y, c4.z, c4.w};
#pragma unroll
            for (int j = 0; j < 8; ++j) {
                float vA = fmaf(avA, wk[j], ck[j]);
                vA = vA > 0.f ? vA : 0.01f * vA;
                aA[s][j] = bfs(vA);
                float vB = fmaf(avB, wk[j], ck[j]);
                vB = vB > 0.f ? vB : 0.01f * vB;
                aB[s][j] = bfs(vB);
            }
        }
        // C-layout acc init: alpha*v2 + b2 (rows = edges q*4+r)
        f32x4 accA[7], accB[7];
#pragma unroll
        for (int r = 0; r < 4; ++r) {
            float arA = __shfl(avA, q * 4 + r, 64);
            float arB = __shfl(avB, q * 4 + r, 64);
#pragma unroll
            for (int t = 0; t < 7; ++t) {
                float vA = fmaf(arA, w1c[t], b1c[t]);
                vA = vA > 0.f ? vA : 0.01f * vA;
                accA[t][r] = fmaf(alpha, vA, b2c[t]);
                float vB = fmaf(arB, w1c[t], b1c[t]);
                vB = vB > 0.f ? vB : 0.01f * vB;
                accB[t][r] = fmaf(alpha, vB, b2c[t]);
            }
        }
        // ---- PHASE 2: v3 MFMAs (shared B reads) ----
#pragma unroll
        for (int s = 0; s < 4; ++s)
#pragma unroll
            for (int t = 0; t < 7; ++t) {
                bf8 bw = *(const bf8*)&sW2f[((t * 4 + s) * 64 + lane) * 8];
                accA[t] = __builtin_amdgcn_mfma_f32_16x16x32_bf16(aA[s], bw, accA[t], 0, 0, 0);
                accB[t] = __builtin_amdgcn_mfma_f32_16x16x32_bf16(aB[s], bw, accB[t], 0, 0, 0);
            }
        // ---- PHASE 3: softmax (no max-reduce; shift-invariant, |v3| small) ----
#pragma unroll
        for (int r = 0; r < 4; ++r) {
            float evA[7], evB[7], sumA = 0.f, sumB = 0.f;
#pragma unroll
            for (int t = 0; t < 7; ++t) {
                bool on = (t < 6) || (ln < 4);
                evA[t] = on ? __expf(accA[t][r]) : 0.f; sumA += evA[t];
                evB[t] = on ? __expf(accB[t][r]) : 0.f; sumB += evB[t];
            }
#pragma unroll
            for (int o = 8; o >= 1; o >>= 1) {
                sumA += __shfl_xor(sumA, o, 16);
                sumB += __shfl_xor(sumB, o, 16);
            }
            float iA = 1.0f / sumA, iB = 1.0f / sumB;
#pragma unroll
            for (int t = 0; t < 7; ++t) { accA[t][r] = evA[t] * iA; accB[t][r] = evB[t] * iB; }
        }
        // ---- PHASE 4: p transposes (zero pad cols 100..127 first; z-stage
        //      clobbered it last iteration) ----
#pragma unroll
        for (int i = 0; i < 7; ++i) {
            int idx = i * 64 + lane;
            int row = idx / 28, c = 100 + (idx - row * 28);
            sB[row * SBS + c] = 0;
        }
#pragma unroll
        for (int r = 0; r < 4; ++r)
#pragma unroll
            for (int t = 0; t < 7; ++t)
                if (t < 6 || ln < 4) sB[(q * 4 + r) * SBS + ln + 16 * t] = bfs(accA[t][r]);
        bf8 apA[4];
#pragma unroll
        for (int s = 0; s < 4; ++s) apA[s] = *(const bf8*)&sB[ln * SBS + 32 * s + 8 * q];
#pragma unroll
        for (int r = 0; r < 4; ++r)
#pragma unroll
            for (int t = 0; t < 7; ++t)
                if (t < 6 || ln < 4) sB[(q * 4 + r) * SBS + ln + 16 * t] = bfs(accB[t][r]);
        bf8 apB[4];
#pragma unroll
        for (int s = 0; s < 4; ++s) apB[s] = *(const bf8*)&sB[ln * SBS + 32 * s + 8 * q];
        // ---- PHASE 5: e = p @ lut (shared B reads) ----
        f32x4 eaccA[4], eaccB[4];
#pragma unroll
        for (int t = 0; t < 4; ++t) {
            eaccA[t] = (f32x4){0.f, 0.f, 0.f, 0.f};
            eaccB[t] = (f32x4){0.f, 0.f, 0.f, 0.f};
        }
#pragma unroll
        for (int s = 0; s < 4; ++s)
#pragma unroll
            for (int t = 0; t < 4; ++t) {
                bf8 bl = *(const bf8*)&sLutf[((t * 4 + s) * 64 + lane) * 8];
                eaccA[t] = __builtin_amdgcn_mfma_f32_16x16x32_bf16(apA[s], bl, eaccA[t], 0, 0, 0);
                eaccB[t] = __builtin_amdgcn_mfma_f32_16x16x32_bf16(apB[s], bl, eaccB[t], 0, 0, 0);
            }
        // ---- PHASE 6: e transposes reuse p's region (cols 0..63; p consumed;
        //      in-order DS makes read-then-overwrite safe) ----
#pragma unroll
        for (int t = 0; t < 4; ++t)
#pragma unroll
            for (int r = 0; r < 4; ++r)
                sB[(q * 4 + r) * SBS + ln + 16 * t] = bfs(eaccA[t][r]);
        acA[4] = *(const bf8*)&sB[ln * SBS + 8 * q];
        acA[5] = *(const bf8*)&sB[ln * SBS + 32 + 8 * q];
#pragma unroll
        for (int t = 0; t < 4; ++t)
#pragma unroll
            for (int r = 0; r < 4; ++r)
                sB[(q * 4 + r) * SBS + ln + 16 * t] = bfs(eaccB[t][r]);
        acB[4] = *(const bf8*)&sB[ln * SBS + 8 * q];
        acB[5] = *(const bf8*)&sB[ln * SBS + 32 + 8 * q];
        // ---- PHASE 7: z = cat @ fcW + fcb (shared B reads) ----
        f32x4 zaccA[8], zaccB[8];
#pragma unroll
        for (int t = 0; t < 8; ++t) {
            zaccA[t] = (f32x4){fbias[t], fbias[t], fbias[t], fbias[t]};
            zaccB[t] = (f32x4){fbias[t], fbias[t], fbias[t], fbias[t]};
        }
#pragma unroll
        for (int s = 0; s < 6; ++s)
#pragma unroll
            for (int t = 0; t < 8; ++t) {
                bf8 bw = *(const bf8*)&sFcf[((s * 8 + t) * 64 + lane) * 8];
                zaccA[t] = __builtin_amdgcn_mfma_f32_16x16x32_bf16(acA[s], bw, zaccA[t], 0, 0, 0);
                zaccB[t] = __builtin_amdgcn_mfma_f32_16x16x32_bf16(acB[s], bw, zaccB[t], 0, 0, 0);
            }
        // ---- PHASE 8: stats + stage + writeout zA ----
#pragma unroll
        for (int t = 0; t < 8; ++t)
#pragma unroll
            for (int r = 0; r < 4; ++r) {
                float zv = zaccA[t][r];
                ss[t] += zv; sq[t] = fmaf(zv, zv, sq[t]);
                sB[(q * 4 + r) * SBS + ln + 16 * t] = bfs(zv);
            }
#pragma unroll
        for (int i = 0; i < 4; ++i) {
            int idx = i * 64 + lane;
            int row = idx >> 4, seg = idx & 15;
            bf8 v = *(const bf8*)&sB[row * SBS + seg * 8];
            *(bf8*)&zo[(size_t)(ebase + row) * 128 + seg * 8] = v;
        }
        // ---- PHASE 9: stats + stage + writeout zB ----
#pragma unroll
        for (int t = 0; t < 8; ++t)
#pragma unroll
            for (int r = 0; r < 4; ++r) {
                float zv = zaccB[t][r];
                ss[t] += zv; sq[t] = fmaf(zv, zv, sq[t]);
                sB[(q * 4 + r) * SBS + ln + 16 * t] = bfs(zv);
            }
#pragma unroll
        for (int i = 0; i < 4; ++i) {
            int idx = i * 64 + lane;
            int row = idx >> 4, seg = idx & 15;
            bf8 v = *(const bf8*)&sB[row * SBS + seg * 8];
            *(bf8*)&zo[(size_t)(ebase + 16 + row) * 128 + seg * 8] = v;
        }
        // ---- rotate prefetched indices ----
        avA = avAN; snA = snAN; dnA = dnAN;
        avB = avBN; snB = snBN; dnB = dnBN;
    }

    // ---- bn1 stats reduction (12 waves) ----
#pragma unroll
    for (int t = 0; t < 8; ++t) {
        ss[t] += __shfl_xor(ss[t], 16, 64); ss[t] += __shfl_xor(ss[t], 32, 64);
        sq[t] += __shfl_xor(sq[t], 16, 64); sq[t] += __shfl_xor(sq[t], 32, 64);
    }
    __syncthreads();
    float* sred = (float*)&sBuf[0][0];    // 3072 floats = 12288 B (fits in sBuf)
    if (q == 0) {
#pragma unroll
        for (int t = 0; t < 8; ++t) {
            sred[wave * 128 + ln + 16 * t] = ss[t];
            sred[1536 + wave * 128 + ln + 16 * t] = sq[t];
        }
    }
    __syncthreads();
    if (tid < 256) {
        int base = (tid < 128) ? 0 : 1536;
        int col = tid & 127;
        float s = 0.f;
#pragma unroll
        for (int w = 0; w < EK_WAVES; ++w) s += sred[base + w * 128 + col];
        atomicAdd(&stats[tid], s);
    }
}

// ------------- bn finalize -------------
__global__ void bn_fin_kernel(const float* __restrict__ stats,
                              const float* __restrict__ g, const float* __restrict__ b,
                              float* __restrict__ bnp, int C, float invN)
{
    int c = threadIdx.x;
    if (c >= C) return;
    float mu = stats[c] * invN;
    float var = stats[C + c] * invN - mu * mu;
    float sc = g[c] * rsqrtf(var + BN_EPS);
    bnp[c] = sc;
    bnp[C + c] = b[c] - mu * sc;
}

// ------------- CSR aggregate: wave per node, zero atomics (R6 proven form) -------------
__global__ __launch_bounds__(256) void aggregate_kernel(
    const unsigned int* __restrict__ z32, const int* __restrict__ rowptr,
    const float* __restrict__ bnp, float* __restrict__ aggr)
{
    const int n = blockIdx.x * 4 + (threadIdx.x >> 6);
    const int lane = threadIdx.x & 63;
    const int f2 = lane & 31, slot = lane >> 5, f = 2 * f2;
    const float sc0 = bnp[f], sc1 = bnp[f + 1];
    const float sh0 = bnp[128 + f], sh1 = bnp[128 + f + 1];
    const float tc0 = bnp[64 + f], tc1 = bnp[64 + f + 1];
    const float th0 = bnp[192 + f], th1 = bnp[192 + f + 1];
    const int s = rowptr[n], e_end = rowptr[n + 1];
    float a0 = 0.f, a1 = 0.f;
    for (int e = s + slot; e < e_end; e += 2) {
        unsigned int ua = z32[(size_t)e * 64 + f2];
        unsigned int ub = z32[(size_t)e * 64 + 32 + f2];
        float zf0 = fmaf(bflo(ua), sc0, sh0);
        float zf1 = fmaf(bfhi(ua), sc1, sh1);
        float zc0 = fmaf(bflo(ub), tc0, th0);
        float zc1 = fmaf(bfhi(ub), tc1, th1);
        a0 += fmaxf(zf0, 0.f) * fmaxf(zc0, 0.f);
        a1 += fmaxf(zf1, 0.f) * fmaxf(zc1, 0.f);
    }
    a0 += __shfl_xor(a0, 32, 64);
    a1 += __shfl_xor(a1, 32, 64);
    if (slot == 0) {
        float2 w; w.x = a0; w.y = a1;
        *(float2*)&aggr[(size_t)n * 64 + f] = w;
    }
}

// ------------- column stats over [rows,64] -------------
__global__ __launch_bounds__(256) void colstats64_kernel(
    const float* __restrict__ x, int rows, float* __restrict__ stats)
{
    int f = threadIdx.x & 63, sub = threadIdx.x >> 6;
    float s = 0.f, q = 0.f;
    for (int r = blockIdx.x * 4 + sub; r < rows; r += gridDim.x * 4) {
        float v = x[(size_t)r * 64 + f];
        s += v; q = fmaf(v, v, q);
    }
    __shared__ float ls[4][64], lq[4][64];
    ls[sub][f] = s; lq[sub][f] = q;
    __syncthreads();
    if (sub == 0) {
        s = ls[0][f] + ls[1][f] + ls[2][f] + ls[3][f];
        q = lq[0][f] + lq[1][f] + lq[2][f] + lq[3][f];
        atomicAdd(&stats[f], s);
        atomicAdd(&stats[64 + f], q);
    }
}

// ------------- h_next = relu(h + bn2(aggr))  (fp32 + bf16 copies) -------------
__global__ __launch_bounds__(256) void update_kernel(
    const float* __restrict__ h, const float* __restrict__ aggr,
    const float* __restrict__ bnp, float* __restrict__ hout,
    unsigned short* __restrict__ hbf)
{
    int t = blockIdx.x * 256 + threadIdx.x;
    int f = t & 63;
    float v = fmaf(aggr[t], bnp[f], bnp[64 + f]);
    float r = fmaxf(h[t] + v, 0.f);
    hout[t] = r;
    hbf[t] = (unsigned short)f2bf(r);
}

// ------------- pooling -------------
__global__ __launch_bounds__(256) void pool_kernel(
    const float* __restrict__ hbuf, const float* __restrict__ ppW,
    const float* __restrict__ ppb, float* __restrict__ out)
{
    const int l = blockIdx.x >> 7, b = blockIdx.x & 127;
    const int wave = threadIdx.x >> 6, lane = threadIdx.x & 63;
    float wcol[64];
#pragma unroll
    for (int k = 0; k < 64; ++k) wcol[k] = ppW[k * 64 + lane];
    const float bias = ppb[lane];
    const float* base = hbuf + ((size_t)l * N_NODES + (size_t)b * 400) * 64;
    __shared__ float srow[4][2][64];
    __shared__ float sacc[4][64];
    float acc = 0.f;
    for (int r = wave * 2; r < 400; r += 8) {
        srow[wave][0][lane] = base[(size_t)r * 64 + lane];
        srow[wave][1][lane] = base[(size_t)r * 64 + 64 + lane];
        float lg0 = bias, lg1 = bias;
#pragma unroll
        for (int k4 = 0; k4 < 64; k4 += 4) {
            float4 a = *(const float4*)&srow[wave][0][k4];
            float4 c = *(const float4*)&srow[wave][1][k4];
            lg0 = fmaf(a.x, wcol[k4 + 0], lg0); lg1 = fmaf(c.x, wcol[k4 + 0], lg1);
            lg0 = fmaf(a.y, wcol[k4 + 1], lg0); lg1 = fmaf(c.y, wcol[k4 + 1], lg1);
            lg0 = fmaf(a.z, wcol[k4 + 2], lg0); lg1 = fmaf(c.z, wcol[k4 + 2], lg1);
            lg0 = fmaf(a.w, wcol[k4 + 3], lg0); lg1 = fmaf(c.w, wcol[k4 + 3], lg1);
        }
        float m0 = lg0, m1 = lg1;
#pragma unroll
        for (int o = 32; o >= 1; o >>= 1) {
            m0 = fmaxf(m0, __shfl_xor(m0, o, 64));
            m1 = fmaxf(m1, __shfl_xor(m1, o, 64));
        }
        float e0 = __expf(lg0 - m0), e1 = __expf(lg1 - m1);
        float s0 = e0, s1 = e1;
#pragma unroll
        for (int o = 32; o >= 1; o >>= 1) {
            s0 += __shfl_xor(s0, o, 64);
            s1 += __shfl_xor(s1, o, 64);
        }
        acc += e0 * (1.0f / s0) + e1 * (1.0f / s1);
    }
    sacc[wave][lane] = acc;
    __syncthreads();
    if (wave == 0) {
        float t = sacc[0][lane] + sacc[1][lane] + sacc[2][lane] + sacc[3][lane];
        atomicAdd(&out[(size_t)b * 64 + lane], t);
    }
}

// ---------------------------------------------------------------------------
extern "C" void kernel_launch(void* const* d_in, const int* in_sizes, int n_in,
                              void* d_out, int out_size, void* d_ws, size_t ws_size,
                              hipStream_t stream)
{
    const float* x        = (const float*)d_in[0];
    const int*   ei       = (const int*)d_in[1];
    const float* ea       = (const float*)d_in[2];
    const float* att      = (const float*)d_in[4];
    const float* embW     = (const float*)d_in[5];
    const float* embB     = (const float*)d_in[6];
    const float* ad_w1    = (const float*)d_in[7];
    const float* ad_b1    = (const float*)d_in[8];
    const float* ad_w2    = (const float*)d_in[9];
    const float* ad_b2    = (const float*)d_in[10];
    const float* ad_alpha = (const float*)d_in[11];
    const float* ad_lut   = (const float*)d_in[12];
    const float* fc_W     = (const float*)d_in[13];
    const float* fc_b     = (const float*)d_in[14];
    const float* bn1_g    = (const float*)d_in[15];
    const float* bn1_b    = (const float*)d_in[16];
    const float* bn2_g    = (const float*)d_in[17];
    const float* bn2_b    = (const float*)d_in[18];
    const float* ppW      = (const float*)d_in[19];
    const float* ppb      = (const float*)d_in[20];
    float* out = (float*)d_out;

    char* ws = (char*)d_ws;
    float* hbuf   = (float*)ws;                          // 52,428,800 B
    short* zU     = (short*)(ws + 52428800);             // 157,286,400 B
    float* aggr   = (float*)(ws + 209715200);            // 13,107,200 B
    float* stats1 = (float*)(ws + 222822400);            // 256 f
    float* bnp1   = stats1 + 256;                        // 256 f
    float* stats2 = bnp1 + 256;                          // 128 f
    float* bnp2   = stats2 + 128;                        // 128 f (pad to 222826496)
    int*   rowptr = (int*)(ws + 222826496);              // 51201 ints
    int*   cursor = (int*)(ws + 223031360);              // 51200 ints
    float* ea_s   = (float*)(ws + 223236160);            // 614400 f
    int*   src_s  = (int*)(ws + 225693760);              // 614400 ints
    int*   dst_s  = (int*)(ws + 228151360);              // 614400 ints
    // perm only used during CSR build (before embed); hbf written after -> union
    int*   perm   = (int*)(ws + 230608960);              // 614400 ints
    unsigned short* hbf = (unsigned short*)(ws + 230608960);   // 6,553,600 B

    // ---- CSR build + sorted edge arrays (dst is launch-constant) ----
    hipMemsetAsync(cursor, 0, N_NODES * sizeof(int), stream);
    hist_kernel<<<N_EDGES / 256, 256, 0, stream>>>(ei, cursor);
    scan_kernel<<<1, 1024, 0, stream>>>(cursor, rowptr);
    permbuild_kernel<<<N_EDGES / 256, 256, 0, stream>>>(ei, cursor, perm);
    gather_sorted_kernel<<<N_EDGES / 256, 256, 0, stream>>>(perm, ea, ei, ea_s, src_s, dst_s);

    hipMemsetAsync(out, 0, 128 * 64 * sizeof(float), stream);
    embed_kernel<<<512, 256, 0, stream>>>(x, att, embW, embB, hbuf, hbf);

    for (int l = 0; l < NCONV; ++l) {
        float* h  = hbuf + (size_t)l * N_NODES * AFL;
        float* hn = h + (size_t)N_NODES * AFL;
        hipMemsetAsync(stats1, 0, 768 * 4, stream);      // zeroes stats1 + bnp1 + stats2
        edge_kernel<<<EK_GRID, EK_BLOCK, 0, stream>>>(
            ea_s, src_s, dst_s, hbf,
            ad_w1 + l * BINS, ad_b1 + l * BINS,
            ad_w2 + l * BINS * BINS, ad_b2 + l * BINS,
            ad_alpha + l, ad_lut + l * BINS * NFL,
            fc_W + l * 192 * 128, fc_b + l * 128,
            zU, stats1);
        bn_fin_kernel<<<1, 128, 0, stream>>>(stats1, bn1_g + l * 128, bn1_b + l * 128,
                                             bnp1, 128, 1.0f / N_EDGES);
        aggregate_kernel<<<N_NODES / 4, 256, 0, stream>>>((const unsigned int*)zU, rowptr,
                                                          bnp1, aggr);
        colstats64_kernel<<<256, 256, 0, stream>>>(aggr, N_NODES, stats2);
        bn_fin_kernel<<<1, 128, 0, stream>>>(stats2, bn2_g + l * 64, bn2_b + l * 64,
                                             bnp2, 64, 1.0f / N_NODES);
        update_kernel<<<N_NODES * 64 / 256, 256, 0, stream>>>(h, aggr, bnp2, hn, hbf);
    }

    pool_kernel<<<512, 256, 0, stream>>>(hbuf, ppW, ppb, out);
}

// Round 15
// 1141.412 us; speedup vs baseline: 1.1259x; 1.1190x over previous
//
#include <hip/hip_runtime.h>

#define N_NODES 51200
#define N_EDGES 614400
#define ORIG 92
#define AFL 64
#define NFL 64
#define BINS 100
#define NCONV 3
#define BN_EPS 1e-5f
#define NTILES (N_EDGES / 16)     // 38400 tiles of 16 edges
#define NGROUPS (NTILES / 2)      // 19200 groups of 2 tiles (32 edges)

typedef __attribute__((ext_vector_type(8))) short bf8;   // 8 bf16 (4 VGPRs)
typedef __attribute__((ext_vector_type(4))) float f32x4;

// ---------- bf16 helpers (bf16 = top 16 bits of fp32, RNE) ----------
__device__ __forceinline__ float bflo(unsigned int u) { return __uint_as_float(u << 16); }
__device__ __forceinline__ float bfhi(unsigned int u) { return __uint_as_float(u & 0xffff0000u); }
__device__ __forceinline__ unsigned int f2bf(float f) {
    unsigned int u = __float_as_uint(f);
    return (u + 0x7fffu + ((u >> 16) & 1u)) >> 16;
}
__device__ __forceinline__ short bfs(float f) { return (short)f2bf(f); }

// ---------------------------- CSR build (once per launch) ----------------------------
__global__ __launch_bounds__(256) void hist_kernel(const int* __restrict__ ei,
                                                   int* __restrict__ cnt)
{
    int e = blockIdx.x * 256 + threadIdx.x;
    atomicAdd(&cnt[ei[N_EDGES + e]], 1);
}

__global__ __launch_bounds__(1024) void scan_kernel(int* __restrict__ cnt_cursor,
                                                    int* __restrict__ rowptr)
{
    __shared__ int part[1024];
    const int t = threadIdx.x;
    const int base = t * 50;
    int s = 0;
#pragma unroll 10
    for (int i = 0; i < 50; ++i) s += cnt_cursor[base + i];
    part[t] = s;
    __syncthreads();
    for (int off = 1; off < 1024; off <<= 1) {
        int v = (t >= off) ? part[t - off] : 0;
        __syncthreads();
        part[t] += v;
        __syncthreads();
    }
    int run = (t == 0) ? 0 : part[t - 1];
    for (int i = 0; i < 50; ++i) {
        int c = cnt_cursor[base + i];
        rowptr[base + i] = run;
        cnt_cursor[base + i] = run;   // cursor init
        run += c;
    }
    if (t == 1023) rowptr[N_NODES] = run;
}

__global__ __launch_bounds__(256) void permbuild_kernel(const int* __restrict__ ei,
                                                        int* __restrict__ cursor,
                                                        int* __restrict__ perm)
{
    int e = blockIdx.x * 256 + threadIdx.x;
    int d = ei[N_EDGES + e];
    int pos = atomicAdd(&cursor[d], 1);
    perm[pos] = e;
}

__global__ __launch_bounds__(256) void gather_sorted_kernel(
    const int* __restrict__ perm, const float* __restrict__ ea,
    const int* __restrict__ ei,
    float* __restrict__ ea_s, int* __restrict__ src_s, int* __restrict__ dst_s)
{
    int i = blockIdx.x * 256 + threadIdx.x;
    int e = perm[i];
    ea_s[i] = ea[e];
    src_s[i] = ei[e];
    dst_s[i] = ei[N_EDGES + e];
}

// ---------------------------- embedding (fp32 + bf16 copies) ----------------------------
__global__ __launch_bounds__(256) void embed_kernel(
    const float* __restrict__ x, const float* __restrict__ att,
    const float* __restrict__ W, const float* __restrict__ b,
    float* __restrict__ h0, unsigned short* __restrict__ hbf)
{
    const int wave = threadIdx.x >> 6, lane = threadIdx.x & 63;
    const int gw = blockIdx.x * 4 + wave;
    const float bv = b[lane];
    for (int n = gw; n < N_NODES; n += gridDim.x * 4) {
        const float* xr = x + (size_t)n * ORIG;
        float acc = bv;
        for (int k = 0; k < ORIG; ++k)
            acc = fmaf(xr[k] * att[k], W[k * AFL + lane], acc);
        h0[(size_t)n * AFL + lane] = acc;
        hbf[(size_t)n * AFL + lane] = (unsigned short)f2bf(acc);
    }
}

// ---------------------------- MFMA edge kernel ----------------------------
// R15: exact revert to R11's measured-best config (187 us, VGPR=128, no
// spills): 512 threads, launch_bounds(512,1), SBS=202 (101 dwords, odd ->
// conflict-free). R12-R14 showed 12-wave blocks cannot reach natural register
// pressure: the allocator's occupancy heuristic squeezes to 84 VGPRs (targeting
// LDS-impossible 2 blocks/CU) and amdgpu_waves_per_eu is ignored alongside
// __launch_bounds__ -> ~300 MB/dispatch scratch spill traffic. 2 waves/SIMD
// with zero spills beats 3 waves/SIMD with spills.
#define SBS 202

__global__ __launch_bounds__(512, 1) void edge_kernel(
    const float* __restrict__ ea_s, const int* __restrict__ src_s,
    const int* __restrict__ dst_s,
    const unsigned short* __restrict__ hbf,
    const float* __restrict__ w1, const float* __restrict__ b1,
    const float* __restrict__ w2, const float* __restrict__ b2,
    const float* __restrict__ alpha_p, const float* __restrict__ lut,
    const float* __restrict__ fcW, const float* __restrict__ fcb,
    short* __restrict__ zo, float* __restrict__ stats)
{
    __shared__ short sW2f[7 * 4 * 64 * 8];    // 28672 B
    __shared__ short sLutf[4 * 4 * 64 * 8];   // 16384 B
    __shared__ short sFcf[6 * 8 * 64 * 8];    // 49152 B
    __shared__ float sW1[128], sB1v[128];     // 1024 B (fp32, zero-padded)
    __shared__ short sBuf[8][16 * SBS];       // 51712 B  total 146944 B

    const int tid = threadIdx.x;
    for (int i = tid; i < 1792; i += 512) {          // W2^T fragments
        int t = i >> 8, rem = i & 255, s = rem >> 6, le = rem & 63;
        int n = 16 * t + (le & 15);
        int kb = 32 * s + ((le >> 4) << 3);
        short* d = &sW2f[i * 8];
#pragma unroll
        for (int j = 0; j < 8; ++j) {
            int k = kb + j;
            d[j] = bfs((n < BINS && k < BINS) ? w2[k * BINS + n] : 0.f);
        }
    }
    for (int i = tid; i < 1024; i += 512) {          // lut^T fragments
        int t = i >> 8, rem = i & 255, s = rem >> 6, le = rem & 63;
        int n = 16 * t + (le & 15);
        int kb = 32 * s + ((le >> 4) << 3);
        short* d = &sLutf[i * 8];
#pragma unroll
        for (int j = 0; j < 8; ++j) {
            int k = kb + j;
            d[j] = bfs(k < BINS ? lut[k * NFL + n] : 0.f);
        }
    }
    for (int i = tid; i < 3072; i += 512) {          // fcW^T fragments
        int s = i >> 9, rem = i & 511, t = rem >> 6, le = rem & 63;
        int n = 16 * t + (le & 15);
        int kb = 32 * s + ((le >> 4) << 3);
        short* d = &sFcf[i * 8];
#pragma unroll
        for (int j = 0; j < 8; ++j)
            d[j] = bfs(fcW[(kb + j) * 128 + n]);
    }
    if (tid < 128) {                                  // w1/b1 fp32, zero-pad k>=100
        sW1[tid]  = (tid < BINS) ? w1[tid] : 0.f;
        sB1v[tid] = (tid < BINS) ? b1[tid] : 0.f;
    }
    __syncthreads();

    const int wave = tid >> 6, lane = tid & 63;
    const int ln = lane & 15, q = lane >> 4;
    short* sB = &sBuf[wave][0];
    const float alpha = alpha_p[0];

    float w1c[7], b1c[7], b2c[7];           // C-layout col = ln + 16t
#pragma unroll
    for (int t = 0; t < 7; ++t) {
        int c = ln + 16 * t;
        bool v = c < BINS;
        w1c[t] = v ? w1[c] : 0.f;
        b1c[t] = v ? b1[c] : 0.f;
        b2c[t] = v ? b2[c] : 0.f;
    }
    float fbias[8];
#pragma unroll
    for (int t = 0; t < 8; ++t) fbias[t] = fcb[ln + 16 * t];

    float ss[8], sq[8];
#pragma unroll
    for (int t = 0; t < 8; ++t) { ss[t] = 0.f; sq[t] = 0.f; }

    int g = blockIdx.x * 8 + wave;
    // ---- prologue: group indices (per-lane: edge ln of each tile) ----
    float avA = 0.f, avB = 0.f;
    int snA = 0, dnA = 0, snB = 0, dnB = 0;
    if (g < NGROUPS) {
        int b0 = g * 32 + ln;
        avA = ea_s[b0];      snA = src_s[b0];      dnA = dst_s[b0];
        avB = ea_s[b0 + 16]; snB = src_s[b0 + 16]; dnB = dst_s[b0 + 16];
    }

    for (; g < NGROUPS; g += 2048) {
        const int ebase = g * 32;
        // ---- PHASE 0: direct per-lane h loads for cat (A-frag layout:
        //      cat[m=ln][k=32s+8q+j], s=0,1 -> h[dst], s=2,3 -> h[src]) ----
        bf8 acA[6], acB[6];
        acA[0] = *(const bf8*)&hbf[(size_t)dnA * 64 + 8 * q];
        acA[1] = *(const bf8*)&hbf[(size_t)dnA * 64 + 32 + 8 * q];
        acA[2] = *(const bf8*)&hbf[(size_t)snA * 64 + 8 * q];
        acA[3] = *(const bf8*)&hbf[(size_t)snA * 64 + 32 + 8 * q];
        acB[0] = *(const bf8*)&hbf[(size_t)dnB * 64 + 8 * q];
        acB[1] = *(const bf8*)&hbf[(size_t)dnB * 64 + 32 + 8 * q];
        acB[2] = *(const bf8*)&hbf[(size_t)snB * 64 + 8 * q];
        acB[3] = *(const bf8*)&hbf[(size_t)snB * 64 + 32 + 8 * q];
        // next-group index prefetch
        const int gn = g + 2048;
        const int gs = (gn < NGROUPS) ? gn : g;
        const int bN = gs * 32 + ln;
        float avAN = ea_s[bN];      int snAN = src_s[bN];      int dnAN = dst_s[bN];
        float avBN = ea_s[bN + 16]; int snBN = src_s[bN + 16]; int dnBN = dst_s[bN + 16];

        // ---- PHASE 1: v2 A-frags DIRECT (av per-lane; w1/b1 broadcast LDS) ----
        bf8 aA[4], aB[4];
#pragma unroll
        for (int s = 0; s < 4; ++s) {
            const int kb = 32 * s + 8 * q;
            float4 w0 = *(const float4*)&sW1[kb];
            float4 w4 = *(const float4*)&sW1[kb + 4];
            float4 c0 = *(const float4*)&sB1v[kb];
            float4 c4 = *(const float4*)&sB1v[kb + 4];
            float wk[8] = {w0.x, w0.y, w0.z, w0.w, w4.x, w4.y, w4.z, w4.w};
            float ck[8] = {c0.x, c0.y, c0.z, c0.w, c4.x, c4.y, c4.z, c4.w};
#pragma unroll
            for (int j = 0; j < 8; ++j) {
                float vA = fmaf(avA, wk[j], ck[j]);
                vA = vA > 0.f ? vA : 0.01f * vA;
                aA[s][j] = bfs(vA);
                float vB = fmaf(avB, wk[j], ck[j]);
                vB = vB > 0.f ? vB : 0.01f * vB;
                aB[s][j] = bfs(vB);
            }
        }
        // C-layout acc init: alpha*v2 + b2 (rows = edges q*4+r)
        f32x4 accA[7], accB[7];
#pragma unroll
        for (int r = 0; r < 4; ++r) {
            float arA = __shfl(avA, q * 4 + r, 64);
            float arB = __shfl(avB, q * 4 + r, 64);
#pragma unroll
            for (int t = 0; t < 7; ++t) {
                float vA = fmaf(arA, w1c[t], b1c[t]);
                vA = vA > 0.f ? vA : 0.01f * vA;
                accA[t][r] = fmaf(alpha, vA, b2c[t]);
                float vB = fmaf(arB, w1c[t], b1c[t]);
                vB = vB > 0.f ? vB : 0.01f * vB;
                accB[t][r] = fmaf(alpha, vB, b2c[t]);
            }
        }
        // ---- PHASE 2: v3 MFMAs (shared B reads) ----
#pragma unroll
        for (int s = 0; s < 4; ++s)
#pragma unroll
            for (int t = 0; t < 7; ++t) {
                bf8 bw = *(const bf8*)&sW2f[((t * 4 + s) * 64 + lane) * 8];
                accA[t] = __builtin_amdgcn_mfma_f32_16x16x32_bf16(aA[s], bw, accA[t], 0, 0, 0);
                accB[t] = __builtin_amdgcn_mfma_f32_16x16x32_bf16(aB[s], bw, accB[t], 0, 0, 0);
            }
        // ---- PHASE 3: softmax (no max-reduce; shift-invariant, |v3| small) ----
#pragma unroll
        for (int r = 0; r < 4; ++r) {
            float evA[7], evB[7], sumA = 0.f, sumB = 0.f;
#pragma unroll
            for (int t = 0; t < 7; ++t) {
                bool on = (t < 6) || (ln < 4);
                evA[t] = on ? __expf(accA[t][r]) : 0.f; sumA += evA[t];
                evB[t] = on ? __expf(accB[t][r]) : 0.f; sumB += evB[t];
            }
#pragma unroll
            for (int o = 8; o >= 1; o >>= 1) {
                sumA += __shfl_xor(sumA, o, 16);
                sumB += __shfl_xor(sumB, o, 16);
            }
            float iA = 1.0f / sumA, iB = 1.0f / sumB;
#pragma unroll
            for (int t = 0; t < 7; ++t) { accA[t][r] = evA[t] * iA; accB[t][r] = evB[t] * iB; }
        }
        // ---- PHASE 4: p transposes (zero pad first; z-stage clobbered it) ----
#pragma unroll
        for (int i = 0; i < 7; ++i) {
            int idx = i * 64 + lane;
            int row = idx / 28, c = 100 + (idx - row * 28);
            sB[row * SBS + c] = 0;
        }
#pragma unroll
        for (int r = 0; r < 4; ++r)
#pragma unroll
            for (int t = 0; t < 7; ++t)
                if (t < 6 || ln < 4) sB[(q * 4 + r) * SBS + ln + 16 * t] = bfs(accA[t][r]);
        bf8 apA[4];
#pragma unroll
        for (int s = 0; s < 4; ++s) apA[s] = *(const bf8*)&sB[ln * SBS + 32 * s + 8 * q];
#pragma unroll
        for (int r = 0; r < 4; ++r)
#pragma unroll
            for (int t = 0; t < 7; ++t)
                if (t < 6 || ln < 4) sB[(q * 4 + r) * SBS + ln + 16 * t] = bfs(accB[t][r]);
        bf8 apB[4];
#pragma unroll
        for (int s = 0; s < 4; ++s) apB[s] = *(const bf8*)&sB[ln * SBS + 32 * s + 8 * q];
        // ---- PHASE 5: e = p @ lut (shared B reads) ----
        f32x4 eaccA[4], eaccB[4];
#pragma unroll
        for (int t = 0; t < 4; ++t) {
            eaccA[t] = (f32x4){0.f, 0.f, 0.f, 0.f};
            eaccB[t] = (f32x4){0.f, 0.f, 0.f, 0.f};
        }
#pragma unroll
        for (int s = 0; s < 4; ++s)
#pragma unroll
            for (int t = 0; t < 4; ++t) {
                bf8 bl = *(const bf8*)&sLutf[((t * 4 + s) * 64 + lane) * 8];
                eaccA[t] = __builtin_amdgcn_mfma_f32_16x16x32_bf16(apA[s], bl, eaccA[t], 0, 0, 0);
                eaccB[t] = __builtin_amdgcn_mfma_f32_16x16x32_bf16(apB[s], bl, eaccB[t], 0, 0, 0);
            }
        // ---- PHASE 6: e transposes (cols 128..191; h-parts already in regs) ----
#pragma unroll
        for (int t = 0; t < 4; ++t)
#pragma unroll
            for (int r = 0; r < 4; ++r)
                sB[(q * 4 + r) * SBS + 128 + ln + 16 * t] = bfs(eaccA[t][r]);
        acA[4] = *(const bf8*)&sB[ln * SBS + 128 + 8 * q];
        acA[5] = *(const bf8*)&sB[ln * SBS + 160 + 8 * q];
#pragma unroll
        for (int t = 0; t < 4; ++t)
#pragma unroll
            for (int r = 0; r < 4; ++r)
                sB[(q * 4 + r) * SBS + 128 + ln + 16 * t] = bfs(eaccB[t][r]);
        acB[4] = *(const bf8*)&sB[ln * SBS + 128 + 8 * q];
        acB[5] = *(const bf8*)&sB[ln * SBS + 160 + 8 * q];
        // ---- PHASE 7: z = cat @ fcW + fcb (shared B reads) ----
        f32x4 zaccA[8], zaccB[8];
#pragma unroll
        for (int t = 0; t < 8; ++t) {
            zaccA[t] = (f32x4){fbias[t], fbias[t], fbias[t], fbias[t]};
            zaccB[t] = (f32x4){fbias[t], fbias[t], fbias[t], fbias[t]};
        }
#pragma unroll
        for (int s = 0; s < 6; ++s)
#pragma unroll
            for (int t = 0; t < 8; ++t) {
                bf8 bw = *(const bf8*)&sFcf[((s * 8 + t) * 64 + lane) * 8];
                zaccA[t] = __builtin_amdgcn_mfma_f32_16x16x32_bf16(acA[s], bw, zaccA[t], 0, 0, 0);
                zaccB[t] = __builtin_amdgcn_mfma_f32_16x16x32_bf16(acB[s], bw, zaccB[t], 0, 0, 0);
            }
        // ---- PHASE 8: stats + stage + writeout zA ----
#pragma unroll
        for (int t = 0; t < 8; ++t)
#pragma unroll
            for (int r = 0; r < 4; ++r) {
                float zv = zaccA[t][r];
                ss[t] += zv; sq[t] = fmaf(zv, zv, sq[t]);
                sB[(q * 4 + r) * SBS + ln + 16 * t] = bfs(zv);
            }
#pragma unroll
        for (int i = 0; i < 4; ++i) {
            int idx = i * 64 + lane;
            int row = idx >> 4, seg = idx & 15;
            bf8 v = *(const bf8*)&sB[row * SBS + seg * 8];
            *(bf8*)&zo[(size_t)(ebase + row) * 128 + seg * 8] = v;
        }
        // ---- PHASE 9: stats + stage + writeout zB ----
#pragma unroll
        for (int t = 0; t < 8; ++t)
#pragma unroll
            for (int r = 0; r < 4; ++r) {
                float zv = zaccB[t][r];
                ss[t] += zv; sq[t] = fmaf(zv, zv, sq[t]);
                sB[(q * 4 + r) * SBS + ln + 16 * t] = bfs(zv);
            }
#pragma unroll
        for (int i = 0; i < 4; ++i) {
            int idx = i * 64 + lane;
            int row = idx >> 4, seg = idx & 15;
            bf8 v = *(const bf8*)&sB[row * SBS + seg * 8];
            *(bf8*)&zo[(size_t)(ebase + 16 + row) * 128 + seg * 8] = v;
        }
        // ---- rotate prefetched indices ----
        avA = avAN; snA = snAN; dnA = dnAN;
        avB = avBN; snB = snBN; dnB = dnBN;
    }

    // ---- bn1 stats reduction ----
#pragma unroll
    for (int t = 0; t < 8; ++t) {
        ss[t] += __shfl_xor(ss[t], 16, 64); ss[t] += __shfl_xor(ss[t], 32, 64);
        sq[t] += __shfl_xor(sq[t], 16, 64); sq[t] += __shfl_xor(sq[t], 32, 64);
    }
    __syncthreads();
    float* sred = (float*)&sBuf[0][0];
    if (q == 0) {
#pragma unroll
        for (int t = 0; t < 8; ++t) {
            sred[wave * 128 + ln + 16 * t] = ss[t];
            sred[1024 + wave * 128 + ln + 16 * t] = sq[t];
        }
    }
    __syncthreads();
    if (tid < 256) {
        int base = (tid < 128) ? 0 : 1024;
        int col = tid & 127;
        float s = 0.f;
#pragma unroll
        for (int w = 0; w < 8; ++w) s += sred[base + w * 128 + col];
        atomicAdd(&stats[tid], s);
    }
}

// ------------- bn finalize -------------
__global__ void bn_fin_kernel(const float* __restrict__ stats,
                              const float* __restrict__ g, const float* __restrict__ b,
                              float* __restrict__ bnp, int C, float invN)
{
    int c = threadIdx.x;
    if (c >= C) return;
    float mu = stats[c] * invN;
    float var = stats[C + c] * invN - mu * mu;
    float sc = g[c] * rsqrtf(var + BN_EPS);
    bnp[c] = sc;
    bnp[C + c] = b[c] - mu * sc;
}

// ------------- CSR aggregate: wave per TWO nodes (interleaved chains for MLP),
//               zero atomics -------------
__global__ __launch_bounds__(256) void aggregate_kernel(
    const unsigned int* __restrict__ z32, const int* __restrict__ rowptr,
    const float* __restrict__ bnp, float* __restrict__ aggr)
{
    const int n0 = (blockIdx.x * 4 + (threadIdx.x >> 6)) * 2;   // two adjacent nodes
    const int lane = threadIdx.x & 63;
    const int f2 = lane & 31, slot = lane >> 5, f = 2 * f2;
    const float sc0 = bnp[f], sc1 = bnp[f + 1];
    const float sh0 = bnp[128 + f], sh1 = bnp[128 + f + 1];
    const float tc0 = bnp[64 + f], tc1 = bnp[64 + f + 1];
    const float th0 = bnp[192 + f], th1 = bnp[192 + f + 1];
    const int s0 = rowptr[n0], m0 = rowptr[n0 + 1], m1 = rowptr[n0 + 2];
    float a0 = 0.f, a1 = 0.f, b0 = 0.f, b1 = 0.f;
    int ea_ = s0 + slot, eb_ = m0 + slot;
    while (ea_ < m0 || eb_ < m1) {
        if (ea_ < m0) {
            unsigned int ua = z32[(size_t)ea_ * 64 + f2];
            unsigned int ub = z32[(size_t)ea_ * 64 + 32 + f2];
            float zf0 = fmaf(bflo(ua), sc0, sh0);
            float zf1 = fmaf(bfhi(ua), sc1, sh1);
            float zc0 = fmaf(bflo(ub), tc0, th0);
            float zc1 = fmaf(bfhi(ub), tc1, th1);
            a0 += fmaxf(zf0, 0.f) * fmaxf(zc0, 0.f);
            a1 += fmaxf(zf1, 0.f) * fmaxf(zc1, 0.f);
        }
        if (eb_ < m1) {
            unsigned int ua = z32[(size_t)eb_ * 64 + f2];
            unsigned int ub = z32[(size_t)eb_ * 64 + 32 + f2];
            float zf0 = fmaf(bflo(ua), sc0, sh0);
            float zf1 = fmaf(bfhi(ua), sc1, sh1);
            float zc0 = fmaf(bflo(ub), tc0, th0);
            float zc1 = fmaf(bfhi(ub), tc1, th1);
            b0 += fmaxf(zf0, 0.f) * fmaxf(zc0, 0.f);
            b1 += fmaxf(zf1, 0.f) * fmaxf(zc1, 0.f);
        }
        ea_ += 2; eb_ += 2;
    }
    a0 += __shfl_xor(a0, 32, 64);
    a1 += __shfl_xor(a1, 32, 64);
    b0 += __shfl_xor(b0, 32, 64);
    b1 += __shfl_xor(b1, 32, 64);
    if (slot == 0) {
        float2 w0; w0.x = a0; w0.y = a1;
        *(float2*)&aggr[(size_t)n0 * 64 + f] = w0;
        float2 w1; w1.x = b0; w1.y = b1;
        *(float2*)&aggr[(size_t)(n0 + 1) * 64 + f] = w1;
    }
}

// ------------- column stats over [rows,64] -------------
__global__ __launch_bounds__(256) void colstats64_kernel(
    const float* __restrict__ x, int rows, float* __restrict__ stats)
{
    int f = threadIdx.x & 63, sub = threadIdx.x >> 6;
    float s = 0.f, q = 0.f;
    for (int r = blockIdx.x * 4 + sub; r < rows; r += gridDim.x * 4) {
        float v = x[(size_t)r * 64 + f];
        s += v; q = fmaf(v, v, q);
    }
    __shared__ float ls[4][64], lq[4][64];
    ls[sub][f] = s; lq[sub][f] = q;
    __syncthreads();
    if (sub == 0) {
        s = ls[0][f] + ls[1][f] + ls[2][f] + ls[3][f];
        q = lq[0][f] + lq[1][f] + lq[2][f] + lq[3][f];
        atomicAdd(&stats[f], s);
        atomicAdd(&stats[64 + f], q);
    }
}

// ------------- h_next = relu(h + bn2(aggr))  (fp32 + bf16 copies) -------------
__global__ __launch_bounds__(256) void update_kernel(
    const float* __restrict__ h, const float* __restrict__ aggr,
    const float* __restrict__ bnp, float* __restrict__ hout,
    unsigned short* __restrict__ hbf)
{
    int t = blockIdx.x * 256 + threadIdx.x;
    int f = t & 63;
    float v = fmaf(aggr[t], bnp[f], bnp[64 + f]);
    float r = fmaxf(h[t] + v, 0.f);
    hout[t] = r;
    hbf[t] = (unsigned short)f2bf(r);
}

// ------------- pooling -------------
__global__ __launch_bounds__(256) void pool_kernel(
    const float* __restrict__ hbuf, const float* __restrict__ ppW,
    const float* __restrict__ ppb, float* __restrict__ out)
{
    const int l = blockIdx.x >> 7, b = blockIdx.x & 127;
    const int wave = threadIdx.x >> 6, lane = threadIdx.x & 63;
    float wcol[64];
#pragma unroll
    for (int k = 0; k < 64; ++k) wcol[k] = ppW[k * 64 + lane];
    const float bias = ppb[lane];
    const float* base = hbuf + ((size_t)l * N_NODES + (size_t)b * 400) * 64;
    __shared__ float srow[4][2][64];
    __shared__ float sacc[4][64];
    float acc = 0.f;
    for (int r = wave * 2; r < 400; r += 8) {
        srow[wave][0][lane] = base[(size_t)r * 64 + lane];
        srow[wave][1][lane] = base[(size_t)r * 64 + 64 + lane];
        float lg0 = bias, lg1 = bias;
#pragma unroll
        for (int k4 = 0; k4 < 64; k4 += 4) {
            float4 a = *(const float4*)&srow[wave][0][k4];
            float4 c = *(const float4*)&srow[wave][1][k4];
            lg0 = fmaf(a.x, wcol[k4 + 0], lg0); lg1 = fmaf(c.x, wcol[k4 + 0], lg1);
            lg0 = fmaf(a.y, wcol[k4 + 1], lg0); lg1 = fmaf(c.y, wcol[k4 + 1], lg1);
            lg0 = fmaf(a.z, wcol[k4 + 2], lg0); lg1 = fmaf(c.z, wcol[k4 + 2], lg1);
            lg0 = fmaf(a.w, wcol[k4 + 3], lg0); lg1 = fmaf(c.w, wcol[k4 + 3], lg1);
        }
        float m0 = lg0, m1 = lg1;
#pragma unroll
        for (int o = 32; o >= 1; o >>= 1) {
            m0 = fmaxf(m0, __shfl_xor(m0, o, 64));
            m1 = fmaxf(m1, __shfl_xor(m1, o, 64));
        }
        float e0 = __expf(lg0 - m0), e1 = __expf(lg1 - m1);
        float s0 = e0, s1 = e1;
#pragma unroll
        for (int o = 32; o >= 1; o >>= 1) {
            s0 += __shfl_xor(s0, o, 64);
            s1 += __shfl_xor(s1, o, 64);
        }
        acc += e0 * (1.0f / s0) + e1 * (1.0f / s1);
    }
    sacc[wave][lane] = acc;
    __syncthreads();
    if (wave == 0) {
        float t = sacc[0][lane] + sacc[1][lane] + sacc[2][lane] + sacc[3][lane];
        atomicAdd(&out[(size_t)b * 64 + lane], t);
    }
}

// ---------------------------------------------------------------------------
extern "C" void kernel_launch(void* const* d_in, const int* in_sizes, int n_in,
                              void* d_out, int out_size, void* d_ws, size_t ws_size,
                              hipStream_t stream)
{
    const float* x        = (const float*)d_in[0];
    const int*   ei       = (const int*)d_in[1];
    const float* ea       = (const float*)d_in[2];
    const float* att      = (const float*)d_in[4];
    const float* embW     = (const float*)d_in[5];
    const float* embB     = (const float*)d_in[6];
    const float* ad_w1    = (const float*)d_in[7];
    const float* ad_b1    = (const float*)d_in[8];
    const float* ad_w2    = (const float*)d_in[9];
    const float* ad_b2    = (const float*)d_in[10];
    const float* ad_alpha = (const float*)d_in[11];
    const float* ad_lut   = (const float*)d_in[12];
    const float* fc_W     = (const float*)d_in[13];
    const float* fc_b     = (const float*)d_in[14];
    const float* bn1_g    = (const float*)d_in[15];
    const float* bn1_b    = (const float*)d_in[16];
    const float* bn2_g    = (const float*)d_in[17];
    const float* bn2_b    = (const float*)d_in[18];
    const float* ppW      = (const float*)d_in[19];
    const float* ppb      = (const float*)d_in[20];
    float* out = (float*)d_out;

    char* ws = (char*)d_ws;
    float* hbuf   = (float*)ws;                          // 52,428,800 B
    short* zU     = (short*)(ws + 52428800);             // 157,286,400 B
    float* aggr   = (float*)(ws + 209715200);            // 13,107,200 B
    float* stats1 = (float*)(ws + 222822400);            // 256 f
    float* bnp1   = stats1 + 256;                        // 256 f
    float* stats2 = bnp1 + 256;                          // 128 f
    float* bnp2   = stats2 + 128;                        // 128 f (pad to 222826496)
    int*   rowptr = (int*)(ws + 222826496);              // 51201 ints
    int*   cursor = (int*)(ws + 223031360);              // 51200 ints
    float* ea_s   = (float*)(ws + 223236160);            // 614400 f
    int*   src_s  = (int*)(ws + 225693760);              // 614400 ints
    int*   dst_s  = (int*)(ws + 228151360);              // 614400 ints
    // perm only used during CSR build (before embed); hbf written after -> union
    int*   perm   = (int*)(ws + 230608960);              // 614400 ints
    unsigned short* hbf = (unsigned short*)(ws + 230608960);   // 6,553,600 B

    // ---- CSR build + sorted edge arrays (dst is launch-constant) ----
    hipMemsetAsync(cursor, 0, N_NODES * sizeof(int), stream);
    hist_kernel<<<N_EDGES / 256, 256, 0, stream>>>(ei, cursor);
    scan_kernel<<<1, 1024, 0, stream>>>(cursor, rowptr);
    permbuild_kernel<<<N_EDGES / 256, 256, 0, stream>>>(ei, cursor, perm);
    gather_sorted_kernel<<<N_EDGES / 256, 256, 0, stream>>>(perm, ea, ei, ea_s, src_s, dst_s);

    hipMemsetAsync(out, 0, 128 * 64 * sizeof(float), stream);
    embed_kernel<<<512, 256, 0, stream>>>(x, att, embW, embB, hbuf, hbf);

    for (int l = 0; l < NCONV; ++l) {
        float* h  = hbuf + (size_t)l * N_NODES * AFL;
        float* hn = h + (size_t)N_NODES * AFL;
        hipMemsetAsync(stats1, 0, 768 * 4, stream);      // zeroes stats1 + bnp1 + stats2
        edge_kernel<<<256, 512, 0, stream>>>(
            ea_s, src_s, dst_s, hbf,
            ad_w1 + l * BINS, ad_b1 + l * BINS,
            ad_w2 + l * BINS * BINS, ad_b2 + l * BINS,
            ad_alpha + l, ad_lut + l * BINS * NFL,
            fc_W + l * 192 * 128, fc_b + l * 128,
            zU, stats1);
        bn_fin_kernel<<<1, 128, 0, stream>>>(stats1, bn1_g + l * 128, bn1_b + l * 128,
                                             bnp1, 128, 1.0f / N_EDGES);
        aggregate_kernel<<<N_NODES / 8, 256, 0, stream>>>((const unsigned int*)zU, rowptr,
                                                          bnp1, aggr);
        colstats64_kernel<<<256, 256, 0, stream>>>(aggr, N_NODES, stats2);
        bn_fin_kernel<<<1, 128, 0, stream>>>(stats2, bn2_g + l * 64, bn2_b + l * 64,
                                             bnp2, 64, 1.0f / N_NODES);
        update_kernel<<<N_NODES * 64 / 256, 256, 0, stream>>>(h, aggr, bnp2, hn, hbf);
    }

    pool_kernel<<<512, 256, 0, stream>>>(hbuf, ppW, ppb, out);
}

// Round 16
// 1116.299 us; speedup vs baseline: 1.1513x; 1.0225x over previous
//
#include <hip/hip_runtime.h>

#define N_NODES 51200
#define N_EDGES 614400
#define ORIG 92
#define AFL 64
#define NFL 64
#define BINS 100
#define NCONV 3
#define BN_EPS 1e-5f
#define NTILES (N_EDGES / 16)     // 38400 tiles of 16 edges
#define NGROUPS (NTILES / 2)      // 19200 groups of 2 tiles (32 edges)

typedef __attribute__((ext_vector_type(8))) short bf8;   // 8 bf16 (4 VGPRs)
typedef __attribute__((ext_vector_type(4))) float f32x4;

// ---------- bf16 helpers (bf16 = top 16 bits of fp32, RNE) ----------
__device__ __forceinline__ float bflo(unsigned int u) { return __uint_as_float(u << 16); }
__device__ __forceinline__ float bfhi(unsigned int u) { return __uint_as_float(u & 0xffff0000u); }
__device__ __forceinline__ unsigned int f2bf(float f) {
    unsigned int u = __float_as_uint(f);
    return (u + 0x7fffu + ((u >> 16) & 1u)) >> 16;
}
__device__ __forceinline__ short bfs(float f) { return (short)f2bf(f); }

// ---------------------------- CSR build (once per launch) ----------------------------
__global__ __launch_bounds__(256) void hist_kernel(const int* __restrict__ ei,
                                                   int* __restrict__ cnt)
{
    int e = blockIdx.x * 256 + threadIdx.x;
    atomicAdd(&cnt[ei[N_EDGES + e]], 1);
}

__global__ __launch_bounds__(1024) void scan_kernel(int* __restrict__ cnt_cursor,
                                                    int* __restrict__ rowptr)
{
    __shared__ int part[1024];
    const int t = threadIdx.x;
    const int base = t * 50;
    int s = 0;
#pragma unroll 10
    for (int i = 0; i < 50; ++i) s += cnt_cursor[base + i];
    part[t] = s;
    __syncthreads();
    for (int off = 1; off < 1024; off <<= 1) {
        int v = (t >= off) ? part[t - off] : 0;
        __syncthreads();
        part[t] += v;
        __syncthreads();
    }
    int run = (t == 0) ? 0 : part[t - 1];
    for (int i = 0; i < 50; ++i) {
        int c = cnt_cursor[base + i];
        rowptr[base + i] = run;
        cnt_cursor[base + i] = run;   // cursor init
        run += c;
    }
    if (t == 1023) rowptr[N_NODES] = run;
}

__global__ __launch_bounds__(256) void permbuild_kernel(const int* __restrict__ ei,
                                                        int* __restrict__ cursor,
                                                        int* __restrict__ perm)
{
    int e = blockIdx.x * 256 + threadIdx.x;
    int d = ei[N_EDGES + e];
    int pos = atomicAdd(&cursor[d], 1);
    perm[pos] = e;
}

__global__ __launch_bounds__(256) void gather_sorted_kernel(
    const int* __restrict__ perm, const float* __restrict__ ea,
    const int* __restrict__ ei,
    float* __restrict__ ea_s, int* __restrict__ src_s, int* __restrict__ dst_s)
{
    int i = blockIdx.x * 256 + threadIdx.x;
    int e = perm[i];
    ea_s[i] = ea[e];
    src_s[i] = ei[e];
    dst_s[i] = ei[N_EDGES + e];
}

// ------------- M = lut @ fcW[128:192]  (one per conv, fragment-linear bf16) -------------
// Mf entry i (per conv): s=i>>9, t=(i&511)>>6, le=i&63; n=16t+(le&15),
// k=32s+((le>>4)<<3)+j. Zero-padded for k>=100.
__global__ __launch_bounds__(256) void prepM_kernel(
    const float* __restrict__ ad_lut, const float* __restrict__ fc_W,
    unsigned short* __restrict__ Mf)
{
    int gi = blockIdx.x * 256 + threadIdx.x;       // 3 * 2048 entries
    int l = gi >> 11;
    int i = gi & 2047;
    int s = i >> 9, rem = i & 511, t = rem >> 6, le = rem & 63;
    int n = 16 * t + (le & 15);
    int kb = 32 * s + ((le >> 4) << 3);
    const float* lut  = ad_lut + (size_t)l * BINS * NFL;
    const float* fcWe = fc_W + (size_t)l * 192 * 128 + 128 * 128;   // rows 128..191
    unsigned short* d = Mf + (size_t)l * 16384 + (size_t)i * 8;
#pragma unroll
    for (int j = 0; j < 8; ++j) {
        int k = kb + j;
        float acc = 0.f;
        if (k < BINS)
            for (int j2 = 0; j2 < 64; ++j2)
                acc = fmaf(lut[k * NFL + j2], fcWe[j2 * 128 + n], acc);
        d[j] = (unsigned short)f2bf(acc);
    }
}

// ---------------------------- embedding (fp32 + bf16 copies) ----------------------------
__global__ __launch_bounds__(256) void embed_kernel(
    const float* __restrict__ x, const float* __restrict__ att,
    const float* __restrict__ W, const float* __restrict__ b,
    float* __restrict__ h0, unsigned short* __restrict__ hbf)
{
    const int wave = threadIdx.x >> 6, lane = threadIdx.x & 63;
    const int gw = blockIdx.x * 4 + wave;
    const float bv = b[lane];
    for (int n = gw; n < N_NODES; n += gridDim.x * 4) {
        const float* xr = x + (size_t)n * ORIG;
        float acc = bv;
        for (int k = 0; k < ORIG; ++k)
            acc = fmaf(xr[k] * att[k], W[k * AFL + lane], acc);
        h0[(size_t)n * AFL + lane] = acc;
        hbf[(size_t)n * AFL + lane] = (unsigned short)f2bf(acc);
    }
}

// ---------------------------- MFMA edge kernel ----------------------------
// R16: e-stage eliminated by associativity: z_e = (p@lut)@fcW_e = p@(lut@fcW_e)
// = p@M with M precomputed per conv (prepM_kernel). The z-GEMM becomes
// s 0..7: A = s<4 ? cat_hh[s] : p[s-4], B = sZW (fcW rows 0..127 ++ M).
// Removes the e-GEMM accumulators and BOTH e LDS round-trips (2 of the 6
// serial DS round-trips per group); MFMA & LDS-B-read counts unchanged.
// Config: R11/R15 proven best (512 thr, launch_bounds(512,1), VGPR=128,
// no spills, SBS=202 = 101 dwords odd -> conflict-free).
#define SBS 202

__global__ __launch_bounds__(512, 1) void edge_kernel(
    const float* __restrict__ ea_s, const int* __restrict__ src_s,
    const int* __restrict__ dst_s,
    const unsigned short* __restrict__ hbf,
    const float* __restrict__ w1, const float* __restrict__ b1,
    const float* __restrict__ w2, const float* __restrict__ b2,
    const float* __restrict__ alpha_p,
    const float* __restrict__ fcW, const float* __restrict__ fcb,
    const unsigned short* __restrict__ Mf,
    short* __restrict__ zo, float* __restrict__ stats)
{
    __shared__ short sW2f[7 * 4 * 64 * 8];    // 28672 B
    __shared__ short sZW[8 * 8 * 64 * 8];     // 65536 B  (s<4: fcW_hh, s>=4: M)
    __shared__ float sW1[128], sB1v[128];     // 1024 B (fp32, zero-padded)
    __shared__ short sBuf[8][16 * SBS];       // 51712 B  total 146944 B

    const int tid = threadIdx.x;
    for (int i = tid; i < 1792; i += 512) {          // W2^T fragments
        int t = i >> 8, rem = i & 255, s = rem >> 6, le = rem & 63;
        int n = 16 * t + (le & 15);
        int kb = 32 * s + ((le >> 4) << 3);
        short* d = &sW2f[i * 8];
#pragma unroll
        for (int j = 0; j < 8; ++j) {
            int k = kb + j;
            d[j] = bfs((n < BINS && k < BINS) ? w2[k * BINS + n] : 0.f);
        }
    }
    for (int i = tid; i < 2048; i += 512) {          // fcW rows 0..127 fragments (s<4)
        int s = i >> 9, rem = i & 511, t = rem >> 6, le = rem & 63;
        int n = 16 * t + (le & 15);
        int kb = 32 * s + ((le >> 4) << 3);
        short* d = &sZW[i * 8];
#pragma unroll
        for (int j = 0; j < 8; ++j)
            d[j] = bfs(fcW[(kb + j) * 128 + n]);
    }
    for (int i = tid; i < 2048; i += 512)            // M fragments (s in 4..7): raw copy
        *(uint4*)&sZW[(2048 + i) * 8] = *(const uint4*)&Mf[(size_t)i * 8];
    if (tid < 128) {                                  // w1/b1 fp32, zero-pad k>=100
        sW1[tid]  = (tid < BINS) ? w1[tid] : 0.f;
        sB1v[tid] = (tid < BINS) ? b1[tid] : 0.f;
    }
    __syncthreads();

    const int wave = tid >> 6, lane = tid & 63;
    const int ln = lane & 15, q = lane >> 4;
    short* sB = &sBuf[wave][0];
    const float alpha = alpha_p[0];

    float w1c[7], b1c[7], b2c[7];           // C-layout col = ln + 16t
#pragma unroll
    for (int t = 0; t < 7; ++t) {
        int c = ln + 16 * t;
        bool v = c < BINS;
        w1c[t] = v ? w1[c] : 0.f;
        b1c[t] = v ? b1[c] : 0.f;
        b2c[t] = v ? b2[c] : 0.f;
    }
    float fbias[8];
#pragma unroll
    for (int t = 0; t < 8; ++t) fbias[t] = fcb[ln + 16 * t];

    float ss[8], sq[8];
#pragma unroll
    for (int t = 0; t < 8; ++t) { ss[t] = 0.f; sq[t] = 0.f; }

    int g = blockIdx.x * 8 + wave;
    // ---- prologue: group indices (per-lane: edge ln of each tile) ----
    float avA = 0.f, avB = 0.f;
    int snA = 0, dnA = 0, snB = 0, dnB = 0;
    if (g < NGROUPS) {
        int b0 = g * 32 + ln;
        avA = ea_s[b0];      snA = src_s[b0];      dnA = dst_s[b0];
        avB = ea_s[b0 + 16]; snB = src_s[b0 + 16]; dnB = dst_s[b0 + 16];
    }

    for (; g < NGROUPS; g += 2048) {
        const int ebase = g * 32;
        // ---- PHASE 0: direct per-lane h loads for cat_hh (A-frag layout:
        //      cat[m=ln][k=32s+8q+j], s=0,1 -> h[dst], s=2,3 -> h[src]) ----
        bf8 acA[4], acB[4];
        acA[0] = *(const bf8*)&hbf[(size_t)dnA * 64 + 8 * q];
        acA[1] = *(const bf8*)&hbf[(size_t)dnA * 64 + 32 + 8 * q];
        acA[2] = *(const bf8*)&hbf[(size_t)snA * 64 + 8 * q];
        acA[3] = *(const bf8*)&hbf[(size_t)snA * 64 + 32 + 8 * q];
        acB[0] = *(const bf8*)&hbf[(size_t)dnB * 64 + 8 * q];
        acB[1] = *(const bf8*)&hbf[(size_t)dnB * 64 + 32 + 8 * q];
        acB[2] = *(const bf8*)&hbf[(size_t)snB * 64 + 8 * q];
        acB[3] = *(const bf8*)&hbf[(size_t)snB * 64 + 32 + 8 * q];
        // next-group index prefetch
        const int gn = g + 2048;
        const int gs = (gn < NGROUPS) ? gn : g;
        const int bN = gs * 32 + ln;
        float avAN = ea_s[bN];      int snAN = src_s[bN];      int dnAN = dst_s[bN];
        float avBN = ea_s[bN + 16]; int snBN = src_s[bN + 16]; int dnBN = dst_s[bN + 16];

        // ---- PHASE 1: v2 A-frags DIRECT (av per-lane; w1/b1 broadcast LDS) ----
        bf8 aA[4], aB[4];
#pragma unroll
        for (int s = 0; s < 4; ++s) {
            const int kb = 32 * s + 8 * q;
            float4 w0 = *(const float4*)&sW1[kb];
            float4 w4 = *(const float4*)&sW1[kb + 4];
            float4 c0 = *(const float4*)&sB1v[kb];
            float4 c4 = *(const float4*)&sB1v[kb + 4];
            float wk[8] = {w0.x, w0.y, w0.z, w0.w, w4.x, w4.y, w4.z, w4.w};
            float ck[8] = {c0.x, c0.y, c0.z, c0.w, c4.x, c4.y, c4.z, c4.w};
#pragma unroll
            for (int j = 0; j < 8; ++j) {
                float vA = fmaf(avA, wk[j], ck[j]);
                vA = vA > 0.f ? vA : 0.01f * vA;
                aA[s][j] = bfs(vA);
                float vB = fmaf(avB, wk[j], ck[j]);
                vB = vB > 0.f ? vB : 0.01f * vB;
                aB[s][j] = bfs(vB);
            }
        }
        // C-layout acc init: alpha*v2 + b2 (rows = edges q*4+r)
        f32x4 accA[7], accB[7];
#pragma unroll
        for (int r = 0; r < 4; ++r) {
            float arA = __shfl(avA, q * 4 + r, 64);
            float arB = __shfl(avB, q * 4 + r, 64);
#pragma unroll
            for (int t = 0; t < 7; ++t) {
                float vA = fmaf(arA, w1c[t], b1c[t]);
                vA = vA > 0.f ? vA : 0.01f * vA;
                accA[t][r] = fmaf(alpha, vA, b2c[t]);
                float vB = fmaf(arB, w1c[t], b1c[t]);
                vB = vB > 0.f ? vB : 0.01f * vB;
                accB[t][r] = fmaf(alpha, vB, b2c[t]);
            }
        }
        // ---- PHASE 2: v3 MFMAs (shared B reads) ----
#pragma unroll
        for (int s = 0; s < 4; ++s)
#pragma unroll
            for (int t = 0; t < 7; ++t) {
                bf8 bw = *(const bf8*)&sW2f[((t * 4 + s) * 64 + lane) * 8];
                accA[t] = __builtin_amdgcn_mfma_f32_16x16x32_bf16(aA[s], bw, accA[t], 0, 0, 0);
                accB[t] = __builtin_amdgcn_mfma_f32_16x16x32_bf16(aB[s], bw, accB[t], 0, 0, 0);
            }
        // ---- PHASE 3: softmax (no max-reduce; shift-invariant, |v3| small) ----
#pragma unroll
        for (int r = 0; r < 4; ++r) {
            float evA[7], evB[7], sumA = 0.f, sumB = 0.f;
#pragma unroll
            for (int t = 0; t < 7; ++t) {
                bool on = (t < 6) || (ln < 4);
                evA[t] = on ? __expf(accA[t][r]) : 0.f; sumA += evA[t];
                evB[t] = on ? __expf(accB[t][r]) : 0.f; sumB += evB[t];
            }
#pragma unroll
            for (int o = 8; o >= 1; o >>= 1) {
                sumA += __shfl_xor(sumA, o, 16);
                sumB += __shfl_xor(sumB, o, 16);
            }
            float iA = 1.0f / sumA, iB = 1.0f / sumB;
#pragma unroll
            for (int t = 0; t < 7; ++t) { accA[t][r] = evA[t] * iA; accB[t][r] = evB[t] * iB; }
        }
        // ---- PHASE 4: p transposes (zero pad cols 100..127 first; z-stage
        //      clobbered it last iteration) ----
#pragma unroll
        for (int i = 0; i < 7; ++i) {
            int idx = i * 64 + lane;
            int row = idx / 28, c = 100 + (idx - row * 28);
            sB[row * SBS + c] = 0;
        }
#pragma unroll
        for (int r = 0; r < 4; ++r)
#pragma unroll
            for (int t = 0; t < 7; ++t)
                if (t < 6 || ln < 4) sB[(q * 4 + r) * SBS + ln + 16 * t] = bfs(accA[t][r]);
        bf8 apA[4];
#pragma unroll
        for (int s = 0; s < 4; ++s) apA[s] = *(const bf8*)&sB[ln * SBS + 32 * s + 8 * q];
#pragma unroll
        for (int r = 0; r < 4; ++r)
#pragma unroll
            for (int t = 0; t < 7; ++t)
                if (t < 6 || ln < 4) sB[(q * 4 + r) * SBS + ln + 16 * t] = bfs(accB[t][r]);
        bf8 apB[4];
#pragma unroll
        for (int s = 0; s < 4; ++s) apB[s] = *(const bf8*)&sB[ln * SBS + 32 * s + 8 * q];
        // ---- PHASE 5: z = [hd|hs]@fcW_hh + p@M + fcb (merged; shared B reads) ----
        f32x4 zaccA[8], zaccB[8];
#pragma unroll
        for (int t = 0; t < 8; ++t) {
            zaccA[t] = (f32x4){fbias[t], fbias[t], fbias[t], fbias[t]};
            zaccB[t] = (f32x4){fbias[t], fbias[t], fbias[t], fbias[t]};
        }
#pragma unroll
        for (int s = 0; s < 8; ++s) {
            bf8 aopA = (s < 4) ? acA[s] : apA[s - 4];
            bf8 aopB = (s < 4) ? acB[s] : apB[s - 4];
#pragma unroll
            for (int t = 0; t < 8; ++t) {
                bf8 bw = *(const bf8*)&sZW[((s * 8 + t) * 64 + lane) * 8];
                zaccA[t] = __builtin_amdgcn_mfma_f32_16x16x32_bf16(aopA, bw, zaccA[t], 0, 0, 0);
                zaccB[t] = __builtin_amdgcn_mfma_f32_16x16x32_bf16(aopB, bw, zaccB[t], 0, 0, 0);
            }
        }
        // ---- PHASE 6: stats + stage + writeout zA ----
#pragma unroll
        for (int t = 0; t < 8; ++t)
#pragma unroll
            for (int r = 0; r < 4; ++r) {
                float zv = zaccA[t][r];
                ss[t] += zv; sq[t] = fmaf(zv, zv, sq[t]);
                sB[(q * 4 + r) * SBS + ln + 16 * t] = bfs(zv);
            }
#pragma unroll
        for (int i = 0; i < 4; ++i) {
            int idx = i * 64 + lane;
            int row = idx >> 4, seg = idx & 15;
            bf8 v = *(const bf8*)&sB[row * SBS + seg * 8];
            *(bf8*)&zo[(size_t)(ebase + row) * 128 + seg * 8] = v;
        }
        // ---- PHASE 7: stats + stage + writeout zB ----
#pragma unroll
        for (int t = 0; t < 8; ++t)
#pragma unroll
            for (int r = 0; r < 4; ++r) {
                float zv = zaccB[t][r];
                ss[t] += zv; sq[t] = fmaf(zv, zv, sq[t]);
                sB[(q * 4 + r) * SBS + ln + 16 * t] = bfs(zv);
            }
#pragma unroll
        for (int i = 0; i < 4; ++i) {
            int idx = i * 64 + lane;
            int row = idx >> 4, seg = idx & 15;
            bf8 v = *(const bf8*)&sB[row * SBS + seg * 8];
            *(bf8*)&zo[(size_t)(ebase + 16 + row) * 128 + seg * 8] = v;
        }
        // ---- rotate prefetched indices ----
        avA = avAN; snA = snAN; dnA = dnAN;
        avB = avBN; snB = snBN; dnB = dnBN;
    }

    // ---- bn1 stats reduction ----
#pragma unroll
    for (int t = 0; t < 8; ++t) {
        ss[t] += __shfl_xor(ss[t], 16, 64); ss[t] += __shfl_xor(ss[t], 32, 64);
        sq[t] += __shfl_xor(sq[t], 16, 64); sq[t] += __shfl_xor(sq[t], 32, 64);
    }
    __syncthreads();
    float* sred = (float*)&sBuf[0][0];
    if (q == 0) {
#pragma unroll
        for (int t = 0; t < 8; ++t) {
            sred[wave * 128 + ln + 16 * t] = ss[t];
            sred[1024 + wave * 128 + ln + 16 * t] = sq[t];
        }
    }
    __syncthreads();
    if (tid < 256) {
        int base = (tid < 128) ? 0 : 1024;
        int col = tid & 127;
        float s = 0.f;
#pragma unroll
        for (int w = 0; w < 8; ++w) s += sred[base + w * 128 + col];
        atomicAdd(&stats[tid], s);
    }
}

// ------------- CSR aggregate: wave per TWO nodes, zero atomics; bn1 finalize
//               fused (per-block redundant compute from stats1) -------------
__global__ __launch_bounds__(256) void aggregate_kernel(
    const unsigned int* __restrict__ z32, const int* __restrict__ rowptr,
    const float* __restrict__ stats1,
    const float* __restrict__ g1, const float* __restrict__ b1g,
    float* __restrict__ aggr)
{
    __shared__ float bnp[256];
    if (threadIdx.x < 128) {
        int c = threadIdx.x;
        float mu = stats1[c] * (1.0f / N_EDGES);
        float var = stats1[128 + c] * (1.0f / N_EDGES) - mu * mu;
        float sc = g1[c] * rsqrtf(var + BN_EPS);
        bnp[c] = sc;
        bnp[128 + c] = b1g[c] - mu * sc;
    }
    __syncthreads();

    const int n0 = (blockIdx.x * 4 + (threadIdx.x >> 6)) * 2;   // two adjacent nodes
    const int lane = threadIdx.x & 63;
    const int f2 = lane & 31, slot = lane >> 5, f = 2 * f2;
    const float sc0 = bnp[f], sc1 = bnp[f + 1];
    const float sh0 = bnp[128 + f], sh1 = bnp[128 + f + 1];
    const float tc0 = bnp[64 + f], tc1 = bnp[64 + f + 1];
    const float th0 = bnp[192 + f], th1 = bnp[192 + f + 1];
    const int s0 = rowptr[n0], m0 = rowptr[n0 + 1], m1 = rowptr[n0 + 2];
    float a0 = 0.f, a1 = 0.f, b0 = 0.f, b1 = 0.f;
    int ea_ = s0 + slot, eb_ = m0 + slot;
    while (ea_ < m0 || eb_ < m1) {
        if (ea_ < m0) {
            unsigned int ua = z32[(size_t)ea_ * 64 + f2];
            unsigned int ub = z32[(size_t)ea_ * 64 + 32 + f2];
            float zf0 = fmaf(bflo(ua), sc0, sh0);
            float zf1 = fmaf(bfhi(ua), sc1, sh1);
            float zc0 = fmaf(bflo(ub), tc0, th0);
            float zc1 = fmaf(bfhi(ub), tc1, th1);
            a0 += fmaxf(zf0, 0.f) * fmaxf(zc0, 0.f);
            a1 += fmaxf(zf1, 0.f) * fmaxf(zc1, 0.f);
        }
        if (eb_ < m1) {
            unsigned int ua = z32[(size_t)eb_ * 64 + f2];
            unsigned int ub = z32[(size_t)eb_ * 64 + 32 + f2];
            float zf0 = fmaf(bflo(ua), sc0, sh0);
            float zf1 = fmaf(bfhi(ua), sc1, sh1);
            float zc0 = fmaf(bflo(ub), tc0, th0);
            float zc1 = fmaf(bfhi(ub), tc1, th1);
            b0 += fmaxf(zf0, 0.f) * fmaxf(zc0, 0.f);
            b1 += fmaxf(zf1, 0.f) * fmaxf(zc1, 0.f);
        }
        ea_ += 2; eb_ += 2;
    }
    a0 += __shfl_xor(a0, 32, 64);
    a1 += __shfl_xor(a1, 32, 64);
    b0 += __shfl_xor(b0, 32, 64);
    b1 += __shfl_xor(b1, 32, 64);
    if (slot == 0) {
        float2 w0; w0.x = a0; w0.y = a1;
        *(float2*)&aggr[(size_t)n0 * 64 + f] = w0;
        float2 w1; w1.x = b0; w1.y = b1;
        *(float2*)&aggr[(size_t)(n0 + 1) * 64 + f] = w1;
    }
}

// ------------- column stats over [rows,64] -------------
__global__ __launch_bounds__(256) void colstats64_kernel(
    const float* __restrict__ x, int rows, float* __restrict__ stats)
{
    int f = threadIdx.x & 63, sub = threadIdx.x >> 6;
    float s = 0.f, q = 0.f;
    for (int r = blockIdx.x * 4 + sub; r < rows; r += gridDim.x * 4) {
        float v = x[(size_t)r * 64 + f];
        s += v; q = fmaf(v, v, q);
    }
    __shared__ float ls[4][64], lq[4][64];
    ls[sub][f] = s; lq[sub][f] = q;
    __syncthreads();
    if (sub == 0) {
        s = ls[0][f] + ls[1][f] + ls[2][f] + ls[3][f];
        q = lq[0][f] + lq[1][f] + lq[2][f] + lq[3][f];
        atomicAdd(&stats[f], s);
        atomicAdd(&stats[64 + f], q);
    }
}

// ------------- h_next = relu(h + bn2(aggr)); bn2 finalize fused -------------
__global__ __launch_bounds__(256) void update_kernel(
    const float* __restrict__ h, const float* __restrict__ aggr,
    const float* __restrict__ stats2,
    const float* __restrict__ g2, const float* __restrict__ b2g,
    float* __restrict__ hout, unsigned short* __restrict__ hbf)
{
    __shared__ float bnp[128];
    if (threadIdx.x < 64) {
        int c = threadIdx.x;
        float mu = stats2[c] * (1.0f / N_NODES);
        float var = stats2[64 + c] * (1.0f / N_NODES) - mu * mu;
        float sc = g2[c] * rsqrtf(var + BN_EPS);
        bnp[c] = sc;
        bnp[64 + c] = b2g[c] - mu * sc;
    }
    __syncthreads();
    int t = blockIdx.x * 256 + threadIdx.x;
    int f = t & 63;
    float v = fmaf(aggr[t], bnp[f], bnp[64 + f]);
    float r = fmaxf(h[t] + v, 0.f);
    hout[t] = r;
    hbf[t] = (unsigned short)f2bf(r);
}

// ------------- pooling -------------
__global__ __launch_bounds__(256) void pool_kernel(
    const float* __restrict__ hbuf, const float* __restrict__ ppW,
    const float* __restrict__ ppb, float* __restrict__ out)
{
    const int l = blockIdx.x >> 7, b = blockIdx.x & 127;
    const int wave = threadIdx.x >> 6, lane = threadIdx.x & 63;
    float wcol[64];
#pragma unroll
    for (int k = 0; k < 64; ++k) wcol[k] = ppW[k * 64 + lane];
    const float bias = ppb[lane];
    const float* base = hbuf + ((size_t)l * N_NODES + (size_t)b * 400) * 64;
    __shared__ float srow[4][2][64];
    __shared__ float sacc[4][64];
    float acc = 0.f;
    for (int r = wave * 2; r < 400; r += 8) {
        srow[wave][0][lane] = base[(size_t)r * 64 + lane];
        srow[wave][1][lane] = base[(size_t)r * 64 + 64 + lane];
        float lg0 = bias, lg1 = bias;
#pragma unroll
        for (int k4 = 0; k4 < 64; k4 += 4) {
            float4 a = *(const float4*)&srow[wave][0][k4];
            float4 c = *(const float4*)&srow[wave][1][k4];
            lg0 = fmaf(a.x, wcol[k4 + 0], lg0); lg1 = fmaf(c.x, wcol[k4 + 0], lg1);
            lg0 = fmaf(a.y, wcol[k4 + 1], lg0); lg1 = fmaf(c.y, wcol[k4 + 1], lg1);
            lg0 = fmaf(a.z, wcol[k4 + 2], lg0); lg1 = fmaf(c.z, wcol[k4 + 2], lg1);
            lg0 = fmaf(a.w, wcol[k4 + 3], lg0); lg1 = fmaf(c.w, wcol[k4 + 3], lg1);
        }
        float m0 = lg0, m1 = lg1;
#pragma unroll
        for (int o = 32; o >= 1; o >>= 1) {
            m0 = fmaxf(m0, __shfl_xor(m0, o, 64));
            m1 = fmaxf(m1, __shfl_xor(m1, o, 64));
        }
        float e0 = __expf(lg0 - m0), e1 = __expf(lg1 - m1);
        float s0 = e0, s1 = e1;
#pragma unroll
        for (int o = 32; o >= 1; o >>= 1) {
            s0 += __shfl_xor(s0, o, 64);
            s1 += __shfl_xor(s1, o, 64);
        }
        acc += e0 * (1.0f / s0) + e1 * (1.0f / s1);
    }
    sacc[wave][lane] = acc;
    __syncthreads();
    if (wave == 0) {
        float t = sacc[0][lane] + sacc[1][lane] + sacc[2][lane] + sacc[3][lane];
        atomicAdd(&out[(size_t)b * 64 + lane], t);
    }
}

// ---------------------------------------------------------------------------
extern "C" void kernel_launch(void* const* d_in, const int* in_sizes, int n_in,
                              void* d_out, int out_size, void* d_ws, size_t ws_size,
                              hipStream_t stream)
{
    const float* x        = (const float*)d_in[0];
    const int*   ei       = (const int*)d_in[1];
    const float* ea       = (const float*)d_in[2];
    const float* att      = (const float*)d_in[4];
    const float* embW     = (const float*)d_in[5];
    const float* embB     = (const float*)d_in[6];
    const float* ad_w1    = (const float*)d_in[7];
    const float* ad_b1    = (const float*)d_in[8];
    const float* ad_w2    = (const float*)d_in[9];
    const float* ad_b2    = (const float*)d_in[10];
    const float* ad_alpha = (const float*)d_in[11];
    const float* ad_lut   = (const float*)d_in[12];
    const float* fc_W     = (const float*)d_in[13];
    const float* fc_b     = (const float*)d_in[14];
    const float* bn1_g    = (const float*)d_in[15];
    const float* bn1_b    = (const float*)d_in[16];
    const float* bn2_g    = (const float*)d_in[17];
    const float* bn2_b    = (const float*)d_in[18];
    const float* ppW      = (const float*)d_in[19];
    const float* ppb      = (const float*)d_in[20];
    float* out = (float*)d_out;

    char* ws = (char*)d_ws;
    float* hbuf   = (float*)ws;                          // 52,428,800 B
    short* zU     = (short*)(ws + 52428800);             // 157,286,400 B
    float* aggr   = (float*)(ws + 209715200);            // 13,107,200 B
    float* stats1 = (float*)(ws + 222822400);            // 256 f
    float* stats2 = stats1 + 256;                        // 128 f  (zeroed together)
    int*   rowptr = (int*)(ws + 222826496);              // 51201 ints
    int*   cursor = (int*)(ws + 223031360);              // 51200 ints
    float* ea_s   = (float*)(ws + 223236160);            // 614400 f
    int*   src_s  = (int*)(ws + 225693760);              // 614400 ints
    int*   dst_s  = (int*)(ws + 228151360);              // 614400 ints
    // perm only used during CSR build (before embed); hbf written after -> union
    int*   perm   = (int*)(ws + 230608960);              // 614400 ints
    unsigned short* hbf = (unsigned short*)(ws + 230608960);   // 6,553,600 B -> ends 237162560
    unsigned short* Mf  = (unsigned short*)(ws + 237162560);   // 3 * 32768 B

    // ---- CSR build + sorted edge arrays (dst is launch-constant) ----
    hipMemsetAsync(cursor, 0, N_NODES * sizeof(int), stream);
    hist_kernel<<<N_EDGES / 256, 256, 0, stream>>>(ei, cursor);
    scan_kernel<<<1, 1024, 0, stream>>>(cursor, rowptr);
    permbuild_kernel<<<N_EDGES / 256, 256, 0, stream>>>(ei, cursor, perm);
    gather_sorted_kernel<<<N_EDGES / 256, 256, 0, stream>>>(perm, ea, ei, ea_s, src_s, dst_s);

    prepM_kernel<<<24, 256, 0, stream>>>(ad_lut, fc_W, Mf);
    hipMemsetAsync(out, 0, 128 * 64 * sizeof(float), stream);
    embed_kernel<<<512, 256, 0, stream>>>(x, att, embW, embB, hbuf, hbf);

    for (int l = 0; l < NCONV; ++l) {
        float* h  = hbuf + (size_t)l * N_NODES * AFL;
        float* hn = h + (size_t)N_NODES * AFL;
        hipMemsetAsync(stats1, 0, 384 * 4, stream);      // stats1 + stats2
        edge_kernel<<<256, 512, 0, stream>>>(
            ea_s, src_s, dst_s, hbf,
            ad_w1 + l * BINS, ad_b1 + l * BINS,
            ad_w2 + l * BINS * BINS, ad_b2 + l * BINS,
            ad_alpha + l,
            fc_W + l * 192 * 128, fc_b + l * 128,
            Mf + (size_t)l * 16384,
            zU, stats1);
        aggregate_kernel<<<N_NODES / 8, 256, 0, stream>>>((const unsigned int*)zU, rowptr,
                                                          stats1, bn1_g + l * 128, bn1_b + l * 128,
                                                          aggr);
        colstats64_kernel<<<256, 256, 0, stream>>>(aggr, N_NODES, stats2);
        update_kernel<<<N_NODES * 64 / 256, 256, 0, stream>>>(h, aggr, stats2,
                                                              bn2_g + l * 64, bn2_b + l * 64,
                                                              hn, hbf);
    }

    pool_kernel<<<512, 256, 0, stream>>>(hbuf, ppW, ppb, out);
}